// Round 9
// baseline (78.031 us; speedup 1.0000x reference)
//
#include <hip/hip_runtime.h>

// Q_RUNLayer_Hybrid: monarch(blockdiag R -> stride perm -> blockdiag L) + bias
// -> LayerNorm -> h + (h@Wd)@Wu -> sin/cos reupload (3) -> [PROJ,6]@Wp.T+bp
// R9: R8's 2-tile software pipeline (1024 thr, 16 waves, 1 wg/CU) with RAW
// barriers (s_waitcnt lgkmcnt(0) + s_barrier, no vmcnt drain) so the P5
// out-stores issued in each pipeline section stay in flight across barriers
// and drain under tile-1's compute. __syncthreads() would drain vmcnt(0) at
// every barrier (hipcc emits the full drain) — that was R8's regression.

typedef __attribute__((ext_vector_type(8))) short bf16x8;
typedef __attribute__((ext_vector_type(4))) float f32x4;

#define PITCH 1032            // ushorts per plane row (1024 + 8 pad)
#define DPITCH 68             // floats per dbuf row
#define DQ (16 * DPITCH)      // 1088 floats per partial group
#define SMEM_BYTES 151808     // 4 planes *33024 + dbuf 17408 + lnpart 2048 + stats 256

__device__ __forceinline__ unsigned short f2bf(float f) {
    unsigned u = __float_as_uint(f);
    u = (u + 0x7FFFu + ((u >> 16) & 1u)) >> 16;   // RNE f32 -> bf16
    return (unsigned short)u;
}
__device__ __forceinline__ float bf2f(unsigned short h) {
    return __uint_as_float(((unsigned)h) << 16);
}
__device__ __forceinline__ unsigned cvt_pk_bf16(float a, float b) {
    unsigned r;                                   // lo16 = bf16(a), hi16 = bf16(b)
    asm("v_cvt_pk_bf16_f32 %0, %1, %2" : "=v"(r) : "v"(a), "v"(b));
    return r;
}
__device__ __forceinline__ void split2(float a, float b, unsigned &H, unsigned &L) {
    H = cvt_pk_bf16(a, b);
    const float ha = __uint_as_float(H << 16);
    const float hb = __uint_as_float(H & 0xFFFF0000u);
    L = cvt_pk_bf16(a - ha, b - hb);
}
__device__ __forceinline__ f32x4 MFMA(bf16x8 a, bf16x8 b, f32x4 c) {
    return __builtin_amdgcn_mfma_f32_16x16x32_bf16(a, b, c, 0, 0, 0);
}
// Raw workgroup barrier: LDS ordering only (lgkmcnt). Deliberately does NOT
// drain vmcnt — global stores have no cross-thread readers here, and global
// loads are register-dep waited at their use sites by the compiler.
__device__ __forceinline__ void barrier_lds() {
    asm volatile("s_waitcnt lgkmcnt(0)\n\ts_barrier" ::: "memory");
}

// ---------------------------------------------------------------------------
// Pack weights into MFMA fragment order (hi/lo bf16). 257 wgs: wg (blk*4+q)
// packs quarter q of 64x64 block blk; wg 256 builds the fixup/param table.
// blk 0..15 = R[b], 16..31 = L[c], 32..47 = Wd' = diag(gamma)Wd, 48..63 = Wu.
// Table at float offset (64*8192 ushorts): bcf[0..63]=B=gamma@Wd,
// bcf[64..127]=C=beta@Wd, bcf[128+p*8+{0..7}] = {gamma,beta,th0',th1',th2',
// ph0',ph1',ph2'} with th'/ph' pre-multiplied by 1/(2*pi).
// Frag addressing (ushorts): blk*8192 + ((kk*4+nt)*2+comp)*512 + lane*8
// element v of lane l:  M[kk*32 + (l>>4)*8 + v][nt*16 + (l&15)]
// ---------------------------------------------------------------------------
__global__ __launch_bounds__(256) void pack_weights(
    const float* __restrict__ R, const float* __restrict__ L,
    const float* __restrict__ Wd, const float* __restrict__ Wu,
    const float* __restrict__ gamma, const float* __restrict__ beta,
    const float* __restrict__ thetas, const float* __restrict__ phis,
    unsigned short* __restrict__ wsp)
{
    const int bx = blockIdx.x;
    const int tid = threadIdx.x;
    if (bx == 256) {
        float* bc = (float*)(wsp + (size_t)64 * 8192);
        const float INV2PI = 0.15915494309189535f;
        for (int i = tid; i < 1024; i += 256) {
            float* t = bc + 128 + i * 8;
            t[0] = gamma[i];                 t[1] = beta[i];
            t[2] = thetas[i] * INV2PI;       t[3] = thetas[1024 + i] * INV2PI;
            t[4] = thetas[2048 + i] * INV2PI;
            t[5] = phis[i] * INV2PI;         t[6] = phis[1024 + i] * INV2PI;
            t[7] = phis[2048 + i] * INV2PI;
        }
        __shared__ float red[8][64];
        const int r = tid & 63, part = tid >> 6;
        float sb = 0.f, sc = 0.f;
        for (int c = part * 256; c < part * 256 + 256; ++c) {
            const float w = Wd[(size_t)c * 64 + r];
            sb += gamma[c] * w;
            sc += beta[c] * w;
        }
        red[part][r] = sb; red[part + 4][r] = sc;
        __syncthreads();
        if (part == 0) {
            bc[r]      = red[0][r] + red[1][r] + red[2][r] + red[3][r];
            bc[64 + r] = red[4][r] + red[5][r] + red[6][r] + red[7][r];
        }
        return;
    }
    const int blk = bx >> 2;
    unsigned short* dst = wsp + (size_t)blk * 8192;
    const int slot = tid + (bx & 3) * 256;     // 0..1023
    const int fragidx = slot >> 6;             // 0..15
    const int l = slot & 63;
    const int kk = fragidx >> 3;
    const int nt = (fragidx >> 1) & 3;
    const int comp = fragidx & 1;
    const int g = l >> 4, r16 = l & 15;
    const int j = nt * 16 + r16;
    bf16x8 s;
    #pragma unroll
    for (int v = 0; v < 8; ++v) {
        const int k = kk * 32 + g * 8 + v;
        float w;
        if (blk < 16)      w = R[(size_t)blk * 4096 + k * 64 + j];
        else if (blk < 32) w = L[(size_t)(blk - 16) * 4096 + k * 64 + j];
        else if (blk < 48) {
            const int kglob = (blk - 32) * 64 + k;
            w = gamma[kglob] * Wd[(size_t)kglob * 64 + j];
        } else             w = Wu[(size_t)k * 1024 + (blk - 48) * 64 + j];
        unsigned short hi = f2bf(w);
        unsigned short bits = (comp == 0) ? hi : f2bf(w - bf2f(hi));
        s[v] = (short)bits;
    }
    *(bf16x8*)(dst + fragidx * 512 + l * 8) = s;
}

// ---------------------------------------------------------------------------
// Fused pipelined kernel. 1024 threads (16 waves), 2 tiles of 16 tokens/wg.
// Wave w: grp4 = w>>2 in {0..3} (splits block/K loops), ntw = w&3.
// ---------------------------------------------------------------------------
__global__ __launch_bounds__(1024, 1) void qrun_main(
    const float* __restrict__ x, const float* __restrict__ bias,
    const float* __restrict__ Wp, const float* __restrict__ bpv,
    const unsigned short* __restrict__ wpk, float* __restrict__ out)
{
    extern __shared__ char smem[];
    unsigned short* hiP0 = (unsigned short*)smem;         // [16][PITCH]
    unsigned short* loP0 = hiP0 + 16 * PITCH;
    unsigned short* hiP1 = loP0 + 16 * PITCH;
    unsigned short* loP1 = hiP1 + 16 * PITCH;
    float* dbuf    = (float*)(loP1 + 16 * PITCH);         // [4][16][DPITCH]
    float* lnpart  = dbuf + 4 * DQ;                       // [16][16][2]
    float* statsR0 = lnpart + 512;                        // [16][2]
    float* statsR1 = statsR0 + 32;                        // [16][2]

    const int tid = threadIdx.x;
    const int wave = tid >> 6, lane = tid & 63;
    const int g = lane >> 4, r16 = lane & 15;
    const int grp4 = wave >> 2, ntw = wave & 3;
    const int rowA = r16 * PITCH;
    const float* bcf = (const float*)(wpk + (size_t)64 * 8192);
    const size_t t0 = (size_t)blockIdx.x * 32;
    const size_t t1 = t0 + 16;

    float wp[24];
    #pragma unroll
    for (int k2 = 0; k2 < 24; ++k2) wp[k2] = Wp[k2];
    const float bp0 = bpv[0], bp1 = bpv[1], bp2 = bpv[2], bp3 = bpv[3];

    auto LOADX = [&](const float* xb, unsigned short* hiP, unsigned short* loP) {
        #pragma unroll
        for (int it = 0; it < 2; ++it) {
            const int base = (it * 1024 + tid) * 8;
            const int row = base >> 10, col = base & 1023;
            const float4 f0 = *(const float4*)(xb + base);
            const float4 f1 = *(const float4*)(xb + base + 4);
            unsigned H0, L0, H1, L1, H2, L2, H3, L3;
            split2(f0.x, f0.y, H0, L0); split2(f0.z, f0.w, H1, L1);
            split2(f1.x, f1.y, H2, L2); split2(f1.z, f1.w, H3, L3);
            *(uint4*)(hiP + row * PITCH + col) = make_uint4(H0, H1, H2, H3);
            *(uint4*)(loP + row * PITCH + col) = make_uint4(L0, L1, L2, L3);
        }
    };

    auto S1 = [&](unsigned short* hiP, unsigned short* loP, f32x4* acc1) {
        #pragma unroll
        for (int bi = 0; bi < 4; ++bi) {
            const int b = grp4 * 4 + bi;
            const unsigned short* wb = wpk + (size_t)b * 8192;
            bf16x8 Bh0 = *(const bf16x8*)(wb + ((0*4+ntw)*2+0)*512 + lane*8);
            bf16x8 Bl0 = *(const bf16x8*)(wb + ((0*4+ntw)*2+1)*512 + lane*8);
            bf16x8 Bh1 = *(const bf16x8*)(wb + ((1*4+ntw)*2+0)*512 + lane*8);
            bf16x8 Bl1 = *(const bf16x8*)(wb + ((1*4+ntw)*2+1)*512 + lane*8);
            const int ca = b * 64 + g * 8;
            bf16x8 Ah0 = *(const bf16x8*)(hiP + rowA + ca);
            bf16x8 Al0 = *(const bf16x8*)(loP + rowA + ca);
            bf16x8 Ah1 = *(const bf16x8*)(hiP + rowA + ca + 32);
            bf16x8 Al1 = *(const bf16x8*)(loP + rowA + ca + 32);
            f32x4 a = {0.f, 0.f, 0.f, 0.f};
            a = MFMA(Ah0, Bh0, a); a = MFMA(Ah0, Bl0, a); a = MFMA(Al0, Bh0, a);
            a = MFMA(Ah1, Bh1, a); a = MFMA(Ah1, Bl1, a); a = MFMA(Al1, Bh1, a);
            acc1[bi] = a;
        }
    };

    // permuted write: b = grp4*4+bi -> dest col c'*64 + kk'*32 + g'swz*8 +
    // (grp4&1)*4 + bi  (4 consecutive cols => uint2 write)
    auto PW = [&](unsigned short* hiP, unsigned short* loP, const f32x4* acc1) {
        const int Cw = (ntw * 4 + (r16 >> 2)) * 64 + ((r16 >> 1) & 1) * 32
                     + ((((grp4 >> 1) + 2 * (r16 & 1)) ^ (r16 >> 2)) << 3)
                     + (grp4 & 1) * 4;
        #pragma unroll
        for (int v = 0; v < 4; ++v) {
            const int rowv = (g * 4 + v) * PITCH;
            unsigned h0, l0, h1, l1;
            split2(acc1[0][v], acc1[1][v], h0, l0);
            split2(acc1[2][v], acc1[3][v], h1, l1);
            *(uint2*)(hiP + rowv + Cw) = make_uint2(h0, h1);
            *(uint2*)(loP + rowv + Cw) = make_uint2(l0, l1);
        }
    };

    auto S2 = [&](unsigned short* hiP, unsigned short* loP, f32x4* acc2) {
        #pragma unroll
        for (int ci = 0; ci < 4; ++ci) {
            const int c = grp4 * 4 + ci;
            const unsigned short* wb = wpk + (size_t)(16 + c) * 8192;
            bf16x8 Wh0 = *(const bf16x8*)(wb + ((0*4+ntw)*2+0)*512 + lane*8);
            bf16x8 Wl0 = *(const bf16x8*)(wb + ((0*4+ntw)*2+1)*512 + lane*8);
            bf16x8 Wh1 = *(const bf16x8*)(wb + ((1*4+ntw)*2+0)*512 + lane*8);
            bf16x8 Wl1 = *(const bf16x8*)(wb + ((1*4+ntw)*2+1)*512 + lane*8);
            const int gx = ((g ^ (c & 3)) << 3);
            const int c0 = rowA + c * 64 + gx;
            bf16x8 Hh0 = *(const bf16x8*)(hiP + c0);
            bf16x8 Hl0 = *(const bf16x8*)(loP + c0);
            bf16x8 Hh1 = *(const bf16x8*)(hiP + c0 + 32);
            bf16x8 Hl1 = *(const bf16x8*)(loP + c0 + 32);
            f32x4 a = {0.f, 0.f, 0.f, 0.f};
            a = MFMA(Wh0, Hh0, a); a = MFMA(Wh0, Hl0, a); a = MFMA(Wl0, Hh0, a);
            a = MFMA(Wh1, Hh1, a); a = MFMA(Wh1, Hl1, a); a = MFMA(Wl1, Hh1, a);
            acc2[ci] = a;
        }
    };

    auto EPI = [&](unsigned short* hiP, unsigned short* loP, const f32x4* acc2) {
        float s = 0.f, s2 = 0.f;
        #pragma unroll
        for (int ci = 0; ci < 4; ++ci) {
            const int c = grp4 * 4 + ci;
            const int ncol = c * 64 + ntw * 16 + g * 4;
            const float4 bv = *(const float4*)(bias + ncol);
            const float f0 = acc2[ci][0] + bv.x;
            const float f1 = acc2[ci][1] + bv.y;
            const float f2 = acc2[ci][2] + bv.z;
            const float f3 = acc2[ci][3] + bv.w;
            s += f0 + f1 + f2 + f3;
            s2 += f0 * f0 + f1 * f1 + f2 * f2 + f3 * f3;
            unsigned hA, lA, hB, lB;
            split2(f0, f1, hA, lA);
            split2(f2, f3, hB, lB);
            *(uint2*)(hiP + rowA + ncol) = make_uint2(hA, hB);
            *(uint2*)(loP + rowA + ncol) = make_uint2(lA, lB);
        }
        s  += __shfl_xor(s, 16);  s  += __shfl_xor(s, 32);
        s2 += __shfl_xor(s2, 16); s2 += __shfl_xor(s2, 32);
        if (g == 0) {
            lnpart[(wave * 16 + r16) * 2]     = s;
            lnpart[(wave * 16 + r16) * 2 + 1] = s2;
        }
    };

    auto STATS_DOWN = [&](unsigned short* hiP, float* statsR) {
        if (tid < 16) {
            float s = 0.f, s2 = 0.f;
            #pragma unroll
            for (int w = 0; w < 16; ++w) {
                s  += lnpart[(w * 16 + tid) * 2];
                s2 += lnpart[(w * 16 + tid) * 2 + 1];
            }
            const float mu = s * (1.f / 1024.f);
            statsR[tid * 2]     = mu;
            statsR[tid * 2 + 1] = rsqrtf(s2 * (1.f / 1024.f) - mu * mu + 1e-5f);
        }
        f32x4 accd = {0.f, 0.f, 0.f, 0.f};
        #pragma unroll
        for (int ki = 0; ki < 8; ++ki) {
            const int kq = grp4 * 8 + ki;
            const int kb = kq >> 1, kin = kq & 1;
            const unsigned short* wb = wpk + (size_t)(32 + kb) * 8192;
            bf16x8 Wh = *(const bf16x8*)(wb + ((kin*4+ntw)*2+0)*512 + lane*8);
            bf16x8 Hh = *(const bf16x8*)(hiP + rowA + kq * 32 + g * 8);
            accd = MFMA(Wh, Hh, accd);
        }
        *(f32x4*)(dbuf + (grp4 * 16 + r16) * DPITCH + ntw * 16 + g * 4) = accd;
    };

    auto FIXUP = [&](const float* statsR, bf16x8* dA, float* muR, float* rsR) {
        const float muT = statsR[r16 * 2], rsT = statsR[r16 * 2 + 1];
        #pragma unroll
        for (int v = 0; v < 4; ++v) {
            muR[v] = statsR[(g * 4 + v) * 2];
            rsR[v] = statsR[(g * 4 + v) * 2 + 1];
        }
        #pragma unroll
        for (int kk = 0; kk < 2; ++kk) {
            const int rb = kk * 32 + g * 8;
            const float4 B0 = *(const float4*)(bcf + rb);
            const float4 B1 = *(const float4*)(bcf + rb + 4);
            const float4 C0 = *(const float4*)(bcf + 64 + rb);
            const float4 C1 = *(const float4*)(bcf + 64 + rb + 4);
            const float Ba[8] = {B0.x,B0.y,B0.z,B0.w,B1.x,B1.y,B1.z,B1.w};
            const float Ca[8] = {C0.x,C0.y,C0.z,C0.w,C1.x,C1.y,C1.z,C1.w};
            const int di = r16 * DPITCH + rb;
            const f32x4 s0 = *(const f32x4*)(dbuf + di)
                           + *(const f32x4*)(dbuf + DQ + di)
                           + *(const f32x4*)(dbuf + 2 * DQ + di)
                           + *(const f32x4*)(dbuf + 3 * DQ + di);
            const f32x4 s1 = *(const f32x4*)(dbuf + di + 4)
                           + *(const f32x4*)(dbuf + DQ + di + 4)
                           + *(const f32x4*)(dbuf + 2 * DQ + di + 4)
                           + *(const f32x4*)(dbuf + 3 * DQ + di + 4);
            float dv[8];
            #pragma unroll
            for (int v = 0; v < 4; ++v) {
                dv[v]     = rsT * s0[v] - muT * rsT * Ba[v]     + Ca[v];
                dv[v + 4] = rsT * s1[v] - muT * rsT * Ba[v + 4] + Ca[v + 4];
            }
            const uint4 uu = make_uint4(cvt_pk_bf16(dv[0], dv[1]),
                                        cvt_pk_bf16(dv[2], dv[3]),
                                        cvt_pk_bf16(dv[4], dv[5]),
                                        cvt_pk_bf16(dv[6], dv[7]));
            dA[kk] = __builtin_bit_cast(bf16x8, uu);
        }
    };

    auto P5J = [&](int j, const unsigned short* hiP, const unsigned short* loP,
                   const bf16x8* dA, const float* muR, const float* rsR,
                   size_t n0) {
        const int ntg = wave * 4 + j;
        const int nb = ntg >> 2, ntin = ntg & 3;
        const unsigned short* wb = wpk + (size_t)(48 + nb) * 8192;
        bf16x8 Bh0 = *(const bf16x8*)(wb + ((0*4+ntin)*2+0)*512 + lane*8);
        bf16x8 Bh1 = *(const bf16x8*)(wb + ((1*4+ntin)*2+0)*512 + lane*8);
        f32x4 au = {0.f, 0.f, 0.f, 0.f};
        au = MFMA(dA[0], Bh0, au);
        au = MFMA(dA[1], Bh1, au);
        const int p = ntg * 16 + r16;
        const float4 tt0 = *(const float4*)(bcf + 128 + p * 8);
        const float4 tt1 = *(const float4*)(bcf + 128 + p * 8 + 4);
        const float gp = tt0.x, bpp = tt0.y;
        const float th0 = tt0.z, th1 = tt0.w, th2 = tt1.x;
        const float ph0 = tt1.y, ph1 = tt1.z, ph2 = tt1.w;
        unsigned short hs[4], ls[4];
        #pragma unroll
        for (int v = 0; v < 4; ++v) {
            const int row = g * 4 + v;
            hs[v] = hiP[row * PITCH + p];
            ls[v] = loP[row * PITCH + p];
        }
        #pragma unroll
        for (int v = 0; v < 4; ++v) {
            const int row = g * 4 + v;
            const float hraw = bf2f(hs[v]) + bf2f(ls[v]);
            const float hn = (hraw - muR[v]) * rsR[v] * gp + bpp;
            const float e = au[v] + hn;
            float o0 = bp0, o1 = bp1, o2 = bp2, o3 = bp3;
            float arg, sn, cs;
            asm("v_fract_f32 %0, %1" : "=v"(arg) : "v"(fmaf(e, th0, ph0)));
            asm("v_sin_f32 %0, %1" : "=v"(sn) : "v"(arg));
            asm("v_cos_f32 %0, %1" : "=v"(cs) : "v"(arg));
            o0 = fmaf(sn, wp[0],  fmaf(cs, wp[1],  o0));
            o1 = fmaf(sn, wp[6],  fmaf(cs, wp[7],  o1));
            o2 = fmaf(sn, wp[12], fmaf(cs, wp[13], o2));
            o3 = fmaf(sn, wp[18], fmaf(cs, wp[19], o3));
            asm("v_fract_f32 %0, %1" : "=v"(arg) : "v"(fmaf(e, th1, ph1)));
            asm("v_sin_f32 %0, %1" : "=v"(sn) : "v"(arg));
            asm("v_cos_f32 %0, %1" : "=v"(cs) : "v"(arg));
            o0 = fmaf(sn, wp[2],  fmaf(cs, wp[3],  o0));
            o1 = fmaf(sn, wp[8],  fmaf(cs, wp[9],  o1));
            o2 = fmaf(sn, wp[14], fmaf(cs, wp[15], o2));
            o3 = fmaf(sn, wp[20], fmaf(cs, wp[21], o3));
            asm("v_fract_f32 %0, %1" : "=v"(arg) : "v"(fmaf(e, th2, ph2)));
            asm("v_sin_f32 %0, %1" : "=v"(sn) : "v"(arg));
            asm("v_cos_f32 %0, %1" : "=v"(cs) : "v"(arg));
            o0 = fmaf(sn, wp[4],  fmaf(cs, wp[5],  o0));
            o1 = fmaf(sn, wp[10], fmaf(cs, wp[11], o1));
            o2 = fmaf(sn, wp[16], fmaf(cs, wp[17], o2));
            o3 = fmaf(sn, wp[22], fmaf(cs, wp[23], o3));
            *(float4*)(out + ((n0 + row) * 1024 + p) * 4) = make_float4(o0, o1, o2, o3);
        }
    };

    // ======================= pipeline (raw barriers) =======================
    f32x4 acc1[4], acc2[4];
    bf16x8 dA0[2], dA1[2];
    float muR0[4], rsR0[4], muR1[4], rsR1[4];

    // tile0 sweep1
    LOADX(x + t0 * 1024, hiP0, loP0);  barrier_lds();
    S1(hiP0, loP0, acc1);              barrier_lds();
    PW(hiP0, loP0, acc1);              barrier_lds();
    S2(hiP0, loP0, acc2);              barrier_lds();
    EPI(hiP0, loP0, acc2);             barrier_lds();
    STATS_DOWN(hiP0, statsR0);
    LOADX(x + t1 * 1024, hiP1, loP1);  barrier_lds();
    FIXUP(statsR0, dA0, muR0, rsR0);

    // tile0 sweep2 (stores, fire-and-forget) interleaved with tile1 sweep1
    P5J(0, hiP0, loP0, dA0, muR0, rsR0, t0);
    S1(hiP1, loP1, acc1);              barrier_lds();
    P5J(1, hiP0, loP0, dA0, muR0, rsR0, t0);
    PW(hiP1, loP1, acc1);              barrier_lds();
    P5J(2, hiP0, loP0, dA0, muR0, rsR0, t0);
    S2(hiP1, loP1, acc2);              barrier_lds();
    P5J(3, hiP0, loP0, dA0, muR0, rsR0, t0);
    EPI(hiP1, loP1, acc2);             barrier_lds();
    STATS_DOWN(hiP1, statsR1);         barrier_lds();
    FIXUP(statsR1, dA1, muR1, rsR1);

    // tile1 sweep2 (tail)
    P5J(0, hiP1, loP1, dA1, muR1, rsR1, t1);
    P5J(1, hiP1, loP1, dA1, muR1, rsR1, t1);
    P5J(2, hiP1, loP1, dA1, muR1, rsR1, t1);
    P5J(3, hiP1, loP1, dA1, muR1, rsR1, t1);
}

extern "C" void kernel_launch(void* const* d_in, const int* in_sizes, int n_in,
                              void* d_out, int out_size, void* d_ws, size_t ws_size,
                              hipStream_t stream) {
    const float* x      = (const float*)d_in[0];
    const float* R      = (const float*)d_in[1];
    const float* L      = (const float*)d_in[2];
    const float* bias   = (const float*)d_in[3];
    const float* gamma  = (const float*)d_in[4];
    const float* beta   = (const float*)d_in[5];
    const float* Wd     = (const float*)d_in[6];
    const float* Wu     = (const float*)d_in[7];
    const float* thetas = (const float*)d_in[8];
    const float* phis   = (const float*)d_in[9];
    const float* Wp     = (const float*)d_in[10];
    const float* bp     = (const float*)d_in[11];
    float* out = (float*)d_out;
    unsigned short* wsp = (unsigned short*)d_ws;
    const int N = in_sizes[0] / 1024;   // 8192 tokens

    (void)hipFuncSetAttribute((const void*)qrun_main,
                              hipFuncAttributeMaxDynamicSharedMemorySize, SMEM_BYTES);
    pack_weights<<<dim3(257), dim3(256), 0, stream>>>(R, L, Wd, Wu, gamma, beta,
                                                      thetas, phis, wsp);
    qrun_main<<<dim3(N / 32), dim3(1024), SMEM_BYTES, stream>>>(
        x, bias, Wp, bp, wsp, out);
}

// Round 10
// 76.781 us; speedup vs baseline: 1.0163x; 1.0163x over previous
//
#include <hip/hip_runtime.h>

// Q_RUNLayer_Hybrid: monarch(blockdiag R -> stride perm -> blockdiag L) + bias
// -> LayerNorm -> h + (h@Wd)@Wu -> sin/cos reupload (3) -> [PROJ,6]@Wp.T+bp
// R10: R9's 2-tile software pipeline (1024 thr, 16 waves, 1 wg/CU, raw
// lgkmcnt-only barriers) + spill fix: amdgpu_waves_per_eu(4,4) pins the VGPR
// budget at 128 (R9's compiler capped at 64 chasing 8 waves/SIMD that LDS
// already forbids -> 34+MB scratch spills, the real R8/R9 regression), and
// wave-uniform wp/bp go through readfirstlane into SGPRs.

typedef __attribute__((ext_vector_type(8))) short bf16x8;
typedef __attribute__((ext_vector_type(4))) float f32x4;

#define PITCH 1032            // ushorts per plane row (1024 + 8 pad)
#define DPITCH 68             // floats per dbuf row
#define DQ (16 * DPITCH)      // 1088 floats per partial group
#define SMEM_BYTES 151808     // 4 planes *33024 + dbuf 17408 + lnpart 2048 + stats 256

__device__ __forceinline__ unsigned short f2bf(float f) {
    unsigned u = __float_as_uint(f);
    u = (u + 0x7FFFu + ((u >> 16) & 1u)) >> 16;   // RNE f32 -> bf16
    return (unsigned short)u;
}
__device__ __forceinline__ float bf2f(unsigned short h) {
    return __uint_as_float(((unsigned)h) << 16);
}
__device__ __forceinline__ unsigned cvt_pk_bf16(float a, float b) {
    unsigned r;                                   // lo16 = bf16(a), hi16 = bf16(b)
    asm("v_cvt_pk_bf16_f32 %0, %1, %2" : "=v"(r) : "v"(a), "v"(b));
    return r;
}
__device__ __forceinline__ void split2(float a, float b, unsigned &H, unsigned &L) {
    H = cvt_pk_bf16(a, b);
    const float ha = __uint_as_float(H << 16);
    const float hb = __uint_as_float(H & 0xFFFF0000u);
    L = cvt_pk_bf16(a - ha, b - hb);
}
__device__ __forceinline__ f32x4 MFMA(bf16x8 a, bf16x8 b, f32x4 c) {
    return __builtin_amdgcn_mfma_f32_16x16x32_bf16(a, b, c, 0, 0, 0);
}
__device__ __forceinline__ float uniformf(float f) {
    return __uint_as_float(__builtin_amdgcn_readfirstlane(__float_as_uint(f)));
}
// Raw workgroup barrier: LDS ordering only (lgkmcnt). Does NOT drain vmcnt —
// global stores have no cross-thread readers; global loads are register-dep
// waited at their use sites by the compiler.
__device__ __forceinline__ void barrier_lds() {
    asm volatile("s_waitcnt lgkmcnt(0)\n\ts_barrier" ::: "memory");
}

// ---------------------------------------------------------------------------
// Pack weights into MFMA fragment order (hi/lo bf16). 257 wgs: wg (blk*4+q)
// packs quarter q of 64x64 block blk; wg 256 builds the fixup/param table.
// blk 0..15 = R[b], 16..31 = L[c], 32..47 = Wd' = diag(gamma)Wd, 48..63 = Wu.
// Table at float offset (64*8192 ushorts): bcf[0..63]=B=gamma@Wd,
// bcf[64..127]=C=beta@Wd, bcf[128+p*8+{0..7}] = {gamma,beta,th0',th1',th2',
// ph0',ph1',ph2'} with th'/ph' pre-multiplied by 1/(2*pi).
// Frag addressing (ushorts): blk*8192 + ((kk*4+nt)*2+comp)*512 + lane*8
// element v of lane l:  M[kk*32 + (l>>4)*8 + v][nt*16 + (l&15)]
// ---------------------------------------------------------------------------
__global__ __launch_bounds__(256) void pack_weights(
    const float* __restrict__ R, const float* __restrict__ L,
    const float* __restrict__ Wd, const float* __restrict__ Wu,
    const float* __restrict__ gamma, const float* __restrict__ beta,
    const float* __restrict__ thetas, const float* __restrict__ phis,
    unsigned short* __restrict__ wsp)
{
    const int bx = blockIdx.x;
    const int tid = threadIdx.x;
    if (bx == 256) {
        float* bc = (float*)(wsp + (size_t)64 * 8192);
        const float INV2PI = 0.15915494309189535f;
        for (int i = tid; i < 1024; i += 256) {
            float* t = bc + 128 + i * 8;
            t[0] = gamma[i];                 t[1] = beta[i];
            t[2] = thetas[i] * INV2PI;       t[3] = thetas[1024 + i] * INV2PI;
            t[4] = thetas[2048 + i] * INV2PI;
            t[5] = phis[i] * INV2PI;         t[6] = phis[1024 + i] * INV2PI;
            t[7] = phis[2048 + i] * INV2PI;
        }
        __shared__ float red[8][64];
        const int r = tid & 63, part = tid >> 6;
        float sb = 0.f, sc = 0.f;
        for (int c = part * 256; c < part * 256 + 256; ++c) {
            const float w = Wd[(size_t)c * 64 + r];
            sb += gamma[c] * w;
            sc += beta[c] * w;
        }
        red[part][r] = sb; red[part + 4][r] = sc;
        __syncthreads();
        if (part == 0) {
            bc[r]      = red[0][r] + red[1][r] + red[2][r] + red[3][r];
            bc[64 + r] = red[4][r] + red[5][r] + red[6][r] + red[7][r];
        }
        return;
    }
    const int blk = bx >> 2;
    unsigned short* dst = wsp + (size_t)blk * 8192;
    const int slot = tid + (bx & 3) * 256;     // 0..1023
    const int fragidx = slot >> 6;             // 0..15
    const int l = slot & 63;
    const int kk = fragidx >> 3;
    const int nt = (fragidx >> 1) & 3;
    const int comp = fragidx & 1;
    const int g = l >> 4, r16 = l & 15;
    const int j = nt * 16 + r16;
    bf16x8 s;
    #pragma unroll
    for (int v = 0; v < 8; ++v) {
        const int k = kk * 32 + g * 8 + v;
        float w;
        if (blk < 16)      w = R[(size_t)blk * 4096 + k * 64 + j];
        else if (blk < 32) w = L[(size_t)(blk - 16) * 4096 + k * 64 + j];
        else if (blk < 48) {
            const int kglob = (blk - 32) * 64 + k;
            w = gamma[kglob] * Wd[(size_t)kglob * 64 + j];
        } else             w = Wu[(size_t)k * 1024 + (blk - 48) * 64 + j];
        unsigned short hi = f2bf(w);
        unsigned short bits = (comp == 0) ? hi : f2bf(w - bf2f(hi));
        s[v] = (short)bits;
    }
    *(bf16x8*)(dst + fragidx * 512 + l * 8) = s;
}

// ---------------------------------------------------------------------------
// Fused pipelined kernel. 1024 threads (16 waves), 2 tiles of 16 tokens/wg.
// Wave w: grp4 = w>>2 in {0..3} (splits block/K loops), ntw = w&3.
// ---------------------------------------------------------------------------
__global__
__attribute__((amdgpu_flat_work_group_size(1024, 1024), amdgpu_waves_per_eu(4, 4)))
void qrun_main(
    const float* __restrict__ x, const float* __restrict__ bias,
    const float* __restrict__ Wp, const float* __restrict__ bpv,
    const unsigned short* __restrict__ wpk, float* __restrict__ out)
{
    extern __shared__ char smem[];
    unsigned short* hiP0 = (unsigned short*)smem;         // [16][PITCH]
    unsigned short* loP0 = hiP0 + 16 * PITCH;
    unsigned short* hiP1 = loP0 + 16 * PITCH;
    unsigned short* loP1 = hiP1 + 16 * PITCH;
    float* dbuf    = (float*)(loP1 + 16 * PITCH);         // [4][16][DPITCH]
    float* lnpart  = dbuf + 4 * DQ;                       // [16][16][2]
    float* statsR0 = lnpart + 512;                        // [16][2]
    float* statsR1 = statsR0 + 32;                        // [16][2]

    const int tid = threadIdx.x;
    const int wave = tid >> 6, lane = tid & 63;
    const int g = lane >> 4, r16 = lane & 15;
    const int grp4 = wave >> 2, ntw = wave & 3;
    const int rowA = r16 * PITCH;
    const float* bcf = (const float*)(wpk + (size_t)64 * 8192);
    const size_t t0 = (size_t)blockIdx.x * 32;
    const size_t t1 = t0 + 16;

    // wave-uniform scalars -> SGPRs via readfirstlane (frees ~28 VGPRs)
    float wp[24];
    #pragma unroll
    for (int k2 = 0; k2 < 24; ++k2) wp[k2] = uniformf(Wp[k2]);
    const float bp0 = uniformf(bpv[0]), bp1 = uniformf(bpv[1]);
    const float bp2 = uniformf(bpv[2]), bp3 = uniformf(bpv[3]);

    auto LOADX = [&](const float* xb, unsigned short* hiP, unsigned short* loP) {
        #pragma unroll
        for (int it = 0; it < 2; ++it) {
            const int base = (it * 1024 + tid) * 8;
            const int row = base >> 10, col = base & 1023;
            const float4 f0 = *(const float4*)(xb + base);
            const float4 f1 = *(const float4*)(xb + base + 4);
            unsigned H0, L0, H1, L1, H2, L2, H3, L3;
            split2(f0.x, f0.y, H0, L0); split2(f0.z, f0.w, H1, L1);
            split2(f1.x, f1.y, H2, L2); split2(f1.z, f1.w, H3, L3);
            *(uint4*)(hiP + row * PITCH + col) = make_uint4(H0, H1, H2, H3);
            *(uint4*)(loP + row * PITCH + col) = make_uint4(L0, L1, L2, L3);
        }
    };

    auto S1 = [&](unsigned short* hiP, unsigned short* loP, f32x4* acc1) {
        #pragma unroll
        for (int bi = 0; bi < 4; ++bi) {
            const int b = grp4 * 4 + bi;
            const unsigned short* wb = wpk + (size_t)b * 8192;
            bf16x8 Bh0 = *(const bf16x8*)(wb + ((0*4+ntw)*2+0)*512 + lane*8);
            bf16x8 Bl0 = *(const bf16x8*)(wb + ((0*4+ntw)*2+1)*512 + lane*8);
            bf16x8 Bh1 = *(const bf16x8*)(wb + ((1*4+ntw)*2+0)*512 + lane*8);
            bf16x8 Bl1 = *(const bf16x8*)(wb + ((1*4+ntw)*2+1)*512 + lane*8);
            const int ca = b * 64 + g * 8;
            bf16x8 Ah0 = *(const bf16x8*)(hiP + rowA + ca);
            bf16x8 Al0 = *(const bf16x8*)(loP + rowA + ca);
            bf16x8 Ah1 = *(const bf16x8*)(hiP + rowA + ca + 32);
            bf16x8 Al1 = *(const bf16x8*)(loP + rowA + ca + 32);
            f32x4 a = {0.f, 0.f, 0.f, 0.f};
            a = MFMA(Ah0, Bh0, a); a = MFMA(Ah0, Bl0, a); a = MFMA(Al0, Bh0, a);
            a = MFMA(Ah1, Bh1, a); a = MFMA(Ah1, Bl1, a); a = MFMA(Al1, Bh1, a);
            acc1[bi] = a;
        }
    };

    // permuted write: b = grp4*4+bi -> dest col c'*64 + kk'*32 + g'swz*8 +
    // (grp4&1)*4 + bi  (4 consecutive cols => uint2 write)
    auto PW = [&](unsigned short* hiP, unsigned short* loP, const f32x4* acc1) {
        const int Cw = (ntw * 4 + (r16 >> 2)) * 64 + ((r16 >> 1) & 1) * 32
                     + ((((grp4 >> 1) + 2 * (r16 & 1)) ^ (r16 >> 2)) << 3)
                     + (grp4 & 1) * 4;
        #pragma unroll
        for (int v = 0; v < 4; ++v) {
            const int rowv = (g * 4 + v) * PITCH;
            unsigned h0, l0, h1, l1;
            split2(acc1[0][v], acc1[1][v], h0, l0);
            split2(acc1[2][v], acc1[3][v], h1, l1);
            *(uint2*)(hiP + rowv + Cw) = make_uint2(h0, h1);
            *(uint2*)(loP + rowv + Cw) = make_uint2(l0, l1);
        }
    };

    auto S2 = [&](unsigned short* hiP, unsigned short* loP, f32x4* acc2) {
        #pragma unroll
        for (int ci = 0; ci < 4; ++ci) {
            const int c = grp4 * 4 + ci;
            const unsigned short* wb = wpk + (size_t)(16 + c) * 8192;
            bf16x8 Wh0 = *(const bf16x8*)(wb + ((0*4+ntw)*2+0)*512 + lane*8);
            bf16x8 Wl0 = *(const bf16x8*)(wb + ((0*4+ntw)*2+1)*512 + lane*8);
            bf16x8 Wh1 = *(const bf16x8*)(wb + ((1*4+ntw)*2+0)*512 + lane*8);
            bf16x8 Wl1 = *(const bf16x8*)(wb + ((1*4+ntw)*2+1)*512 + lane*8);
            const int gx = ((g ^ (c & 3)) << 3);
            const int c0 = rowA + c * 64 + gx;
            bf16x8 Hh0 = *(const bf16x8*)(hiP + c0);
            bf16x8 Hl0 = *(const bf16x8*)(loP + c0);
            bf16x8 Hh1 = *(const bf16x8*)(hiP + c0 + 32);
            bf16x8 Hl1 = *(const bf16x8*)(loP + c0 + 32);
            f32x4 a = {0.f, 0.f, 0.f, 0.f};
            a = MFMA(Wh0, Hh0, a); a = MFMA(Wh0, Hl0, a); a = MFMA(Wl0, Hh0, a);
            a = MFMA(Wh1, Hh1, a); a = MFMA(Wh1, Hl1, a); a = MFMA(Wl1, Hh1, a);
            acc2[ci] = a;
        }
    };

    auto EPI = [&](unsigned short* hiP, unsigned short* loP, const f32x4* acc2) {
        float s = 0.f, s2 = 0.f;
        #pragma unroll
        for (int ci = 0; ci < 4; ++ci) {
            const int c = grp4 * 4 + ci;
            const int ncol = c * 64 + ntw * 16 + g * 4;
            const float4 bv = *(const float4*)(bias + ncol);
            const float f0 = acc2[ci][0] + bv.x;
            const float f1 = acc2[ci][1] + bv.y;
            const float f2 = acc2[ci][2] + bv.z;
            const float f3 = acc2[ci][3] + bv.w;
            s += f0 + f1 + f2 + f3;
            s2 += f0 * f0 + f1 * f1 + f2 * f2 + f3 * f3;
            unsigned hA, lA, hB, lB;
            split2(f0, f1, hA, lA);
            split2(f2, f3, hB, lB);
            *(uint2*)(hiP + rowA + ncol) = make_uint2(hA, hB);
            *(uint2*)(loP + rowA + ncol) = make_uint2(lA, lB);
        }
        s  += __shfl_xor(s, 16);  s  += __shfl_xor(s, 32);
        s2 += __shfl_xor(s2, 16); s2 += __shfl_xor(s2, 32);
        if (g == 0) {
            lnpart[(wave * 16 + r16) * 2]     = s;
            lnpart[(wave * 16 + r16) * 2 + 1] = s2;
        }
    };

    auto STATS_DOWN = [&](unsigned short* hiP, float* statsR) {
        if (tid < 16) {
            float s = 0.f, s2 = 0.f;
            #pragma unroll
            for (int w = 0; w < 16; ++w) {
                s  += lnpart[(w * 16 + tid) * 2];
                s2 += lnpart[(w * 16 + tid) * 2 + 1];
            }
            const float mu = s * (1.f / 1024.f);
            statsR[tid * 2]     = mu;
            statsR[tid * 2 + 1] = rsqrtf(s2 * (1.f / 1024.f) - mu * mu + 1e-5f);
        }
        f32x4 accd = {0.f, 0.f, 0.f, 0.f};
        #pragma unroll
        for (int ki = 0; ki < 8; ++ki) {
            const int kq = grp4 * 8 + ki;
            const int kb = kq >> 1, kin = kq & 1;
            const unsigned short* wb = wpk + (size_t)(32 + kb) * 8192;
            bf16x8 Wh = *(const bf16x8*)(wb + ((kin*4+ntw)*2+0)*512 + lane*8);
            bf16x8 Hh = *(const bf16x8*)(hiP + rowA + kq * 32 + g * 8);
            accd = MFMA(Wh, Hh, accd);
        }
        *(f32x4*)(dbuf + (grp4 * 16 + r16) * DPITCH + ntw * 16 + g * 4) = accd;
    };

    auto FIXUP = [&](const float* statsR, bf16x8* dA, float* muR, float* rsR) {
        const float muT = statsR[r16 * 2], rsT = statsR[r16 * 2 + 1];
        #pragma unroll
        for (int v = 0; v < 4; ++v) {
            muR[v] = statsR[(g * 4 + v) * 2];
            rsR[v] = statsR[(g * 4 + v) * 2 + 1];
        }
        #pragma unroll
        for (int kk = 0; kk < 2; ++kk) {
            const int rb = kk * 32 + g * 8;
            const float4 B0 = *(const float4*)(bcf + rb);
            const float4 B1 = *(const float4*)(bcf + rb + 4);
            const float4 C0 = *(const float4*)(bcf + 64 + rb);
            const float4 C1 = *(const float4*)(bcf + 64 + rb + 4);
            const float Ba[8] = {B0.x,B0.y,B0.z,B0.w,B1.x,B1.y,B1.z,B1.w};
            const float Ca[8] = {C0.x,C0.y,C0.z,C0.w,C1.x,C1.y,C1.z,C1.w};
            const int di = r16 * DPITCH + rb;
            const f32x4 s0 = *(const f32x4*)(dbuf + di)
                           + *(const f32x4*)(dbuf + DQ + di)
                           + *(const f32x4*)(dbuf + 2 * DQ + di)
                           + *(const f32x4*)(dbuf + 3 * DQ + di);
            const f32x4 s1 = *(const f32x4*)(dbuf + di + 4)
                           + *(const f32x4*)(dbuf + DQ + di + 4)
                           + *(const f32x4*)(dbuf + 2 * DQ + di + 4)
                           + *(const f32x4*)(dbuf + 3 * DQ + di + 4);
            float dv[8];
            #pragma unroll
            for (int v = 0; v < 4; ++v) {
                dv[v]     = rsT * s0[v] - muT * rsT * Ba[v]     + Ca[v];
                dv[v + 4] = rsT * s1[v] - muT * rsT * Ba[v + 4] + Ca[v + 4];
            }
            const uint4 uu = make_uint4(cvt_pk_bf16(dv[0], dv[1]),
                                        cvt_pk_bf16(dv[2], dv[3]),
                                        cvt_pk_bf16(dv[4], dv[5]),
                                        cvt_pk_bf16(dv[6], dv[7]));
            dA[kk] = __builtin_bit_cast(bf16x8, uu);
        }
    };

    auto P5J = [&](int j, const unsigned short* hiP, const unsigned short* loP,
                   const bf16x8* dA, const float* muR, const float* rsR,
                   size_t n0) {
        const int ntg = wave * 4 + j;
        const int nb = ntg >> 2, ntin = ntg & 3;
        const unsigned short* wb = wpk + (size_t)(48 + nb) * 8192;
        bf16x8 Bh0 = *(const bf16x8*)(wb + ((0*4+ntin)*2+0)*512 + lane*8);
        bf16x8 Bh1 = *(const bf16x8*)(wb + ((1*4+ntin)*2+0)*512 + lane*8);
        f32x4 au = {0.f, 0.f, 0.f, 0.f};
        au = MFMA(dA[0], Bh0, au);
        au = MFMA(dA[1], Bh1, au);
        const int p = ntg * 16 + r16;
        const float4 tt0 = *(const float4*)(bcf + 128 + p * 8);
        const float4 tt1 = *(const float4*)(bcf + 128 + p * 8 + 4);
        const float gp = tt0.x, bpp = tt0.y;
        const float th0 = tt0.z, th1 = tt0.w, th2 = tt1.x;
        const float ph0 = tt1.y, ph1 = tt1.z, ph2 = tt1.w;
        unsigned short hs[4], ls[4];
        #pragma unroll
        for (int v = 0; v < 4; ++v) {
            const int row = g * 4 + v;
            hs[v] = hiP[row * PITCH + p];
            ls[v] = loP[row * PITCH + p];
        }
        #pragma unroll
        for (int v = 0; v < 4; ++v) {
            const int row = g * 4 + v;
            const float hraw = bf2f(hs[v]) + bf2f(ls[v]);
            const float hn = (hraw - muR[v]) * rsR[v] * gp + bpp;
            const float e = au[v] + hn;
            float o0 = bp0, o1 = bp1, o2 = bp2, o3 = bp3;
            float arg, sn, cs;
            asm("v_fract_f32 %0, %1" : "=v"(arg) : "v"(fmaf(e, th0, ph0)));
            asm("v_sin_f32 %0, %1" : "=v"(sn) : "v"(arg));
            asm("v_cos_f32 %0, %1" : "=v"(cs) : "v"(arg));
            o0 = fmaf(sn, wp[0],  fmaf(cs, wp[1],  o0));
            o1 = fmaf(sn, wp[6],  fmaf(cs, wp[7],  o1));
            o2 = fmaf(sn, wp[12], fmaf(cs, wp[13], o2));
            o3 = fmaf(sn, wp[18], fmaf(cs, wp[19], o3));
            asm("v_fract_f32 %0, %1" : "=v"(arg) : "v"(fmaf(e, th1, ph1)));
            asm("v_sin_f32 %0, %1" : "=v"(sn) : "v"(arg));
            asm("v_cos_f32 %0, %1" : "=v"(cs) : "v"(arg));
            o0 = fmaf(sn, wp[2],  fmaf(cs, wp[3],  o0));
            o1 = fmaf(sn, wp[8],  fmaf(cs, wp[9],  o1));
            o2 = fmaf(sn, wp[14], fmaf(cs, wp[15], o2));
            o3 = fmaf(sn, wp[20], fmaf(cs, wp[21], o3));
            asm("v_fract_f32 %0, %1" : "=v"(arg) : "v"(fmaf(e, th2, ph2)));
            asm("v_sin_f32 %0, %1" : "=v"(sn) : "v"(arg));
            asm("v_cos_f32 %0, %1" : "=v"(cs) : "v"(arg));
            o0 = fmaf(sn, wp[4],  fmaf(cs, wp[5],  o0));
            o1 = fmaf(sn, wp[10], fmaf(cs, wp[11], o1));
            o2 = fmaf(sn, wp[16], fmaf(cs, wp[17], o2));
            o3 = fmaf(sn, wp[22], fmaf(cs, wp[23], o3));
            *(float4*)(out + ((n0 + row) * 1024 + p) * 4) = make_float4(o0, o1, o2, o3);
        }
    };

    // ======================= pipeline (raw barriers) =======================
    f32x4 acc1[4], acc2[4];
    bf16x8 dA0[2], dA1[2];
    float muR0[4], rsR0[4], muR1[4], rsR1[4];

    // tile0 sweep1
    LOADX(x + t0 * 1024, hiP0, loP0);  barrier_lds();
    S1(hiP0, loP0, acc1);              barrier_lds();
    PW(hiP0, loP0, acc1);              barrier_lds();
    S2(hiP0, loP0, acc2);              barrier_lds();
    EPI(hiP0, loP0, acc2);             barrier_lds();
    STATS_DOWN(hiP0, statsR0);
    LOADX(x + t1 * 1024, hiP1, loP1);  barrier_lds();
    FIXUP(statsR0, dA0, muR0, rsR0);

    // tile0 sweep2 (stores, fire-and-forget) interleaved with tile1 sweep1
    P5J(0, hiP0, loP0, dA0, muR0, rsR0, t0);
    S1(hiP1, loP1, acc1);              barrier_lds();
    P5J(1, hiP0, loP0, dA0, muR0, rsR0, t0);
    PW(hiP1, loP1, acc1);              barrier_lds();
    P5J(2, hiP0, loP0, dA0, muR0, rsR0, t0);
    S2(hiP1, loP1, acc2);              barrier_lds();
    P5J(3, hiP0, loP0, dA0, muR0, rsR0, t0);
    EPI(hiP1, loP1, acc2);             barrier_lds();
    STATS_DOWN(hiP1, statsR1);         barrier_lds();
    FIXUP(statsR1, dA1, muR1, rsR1);

    // tile1 sweep2 (tail)
    P5J(0, hiP1, loP1, dA1, muR1, rsR1, t1);
    P5J(1, hiP1, loP1, dA1, muR1, rsR1, t1);
    P5J(2, hiP1, loP1, dA1, muR1, rsR1, t1);
    P5J(3, hiP1, loP1, dA1, muR1, rsR1, t1);
}

extern "C" void kernel_launch(void* const* d_in, const int* in_sizes, int n_in,
                              void* d_out, int out_size, void* d_ws, size_t ws_size,
                              hipStream_t stream) {
    const float* x      = (const float*)d_in[0];
    const float* R      = (const float*)d_in[1];
    const float* L      = (const float*)d_in[2];
    const float* bias   = (const float*)d_in[3];
    const float* gamma  = (const float*)d_in[4];
    const float* beta   = (const float*)d_in[5];
    const float* Wd     = (const float*)d_in[6];
    const float* Wu     = (const float*)d_in[7];
    const float* thetas = (const float*)d_in[8];
    const float* phis   = (const float*)d_in[9];
    const float* Wp     = (const float*)d_in[10];
    const float* bp     = (const float*)d_in[11];
    float* out = (float*)d_out;
    unsigned short* wsp = (unsigned short*)d_ws;
    const int N = in_sizes[0] / 1024;   // 8192 tokens

    (void)hipFuncSetAttribute((const void*)qrun_main,
                              hipFuncAttributeMaxDynamicSharedMemorySize, SMEM_BYTES);
    pack_weights<<<dim3(257), dim3(256), 0, stream>>>(R, L, Wd, Wu, gamma, beta,
                                                      thetas, phis, wsp);
    qrun_main<<<dim3(N / 32), dim3(1024), SMEM_BYTES, stream>>>(
        x, bias, Wp, bp, wsp, out);
}

// Round 12
// 58.136 us; speedup vs baseline: 1.3422x; 1.3207x over previous
//
#include <hip/hip_runtime.h>

// Q_RUNLayer_Hybrid: monarch(blockdiag R -> stride perm -> blockdiag L) + bias
// -> LayerNorm -> h + (h@Wd)@Wu -> sin/cos reupload (3) -> [PROJ,6]@Wp.T+bp
// R12 = R6 skeleton (16 tok/wg, 512 thr, 2 wg/CU, LDS-staged x, __syncthreads
// chain) + NON-TEMPORAL x loads and out stores: the 168 MB touch-once stream
// otherwise evicts the 1 MB packed-weight set from the 4 MB/XCD L2 between
// phases (each wg re-reads ~400 KB of weights across its lifetime).
// Split-bf16 via v_cvt_pk_bf16_f32; LayerNorm folded into down-proj
// (Wd' = diag(gamma)Wd; fixup B=gamma@Wd, C=beta@Wd); packed per-p param
// table with 1/(2pi)-folded thetas/phis for v_fract/v_sin/v_cos.
// NOTE: direct-global-x in S1 is RETIRED (R5+R11 both fail ~0.95 absmax,
// mechanism unidentified — keep x staged through LDS).

typedef __attribute__((ext_vector_type(8))) short bf16x8;
typedef __attribute__((ext_vector_type(4))) float f32x4;

#define PITCH 1032            // ushorts per plane row (1024 + 8 pad)
#define DPITCH 68             // floats per dbuf row
#define DHALF (16 * DPITCH)   // 1088
#define SMEM_BYTES 75904      // 2*16*1032*2 + 2*1088*4 + 256*4 + 32*4

__device__ __forceinline__ unsigned short f2bf(float f) {
    unsigned u = __float_as_uint(f);
    u = (u + 0x7FFFu + ((u >> 16) & 1u)) >> 16;   // RNE f32 -> bf16
    return (unsigned short)u;
}
__device__ __forceinline__ float bf2f(unsigned short h) {
    return __uint_as_float(((unsigned)h) << 16);
}
__device__ __forceinline__ unsigned cvt_pk_bf16(float a, float b) {
    unsigned r;                                   // lo16 = bf16(a), hi16 = bf16(b)
    asm("v_cvt_pk_bf16_f32 %0, %1, %2" : "=v"(r) : "v"(a), "v"(b));
    return r;
}
// split (a,b) -> packed hi u32 + packed lo u32 (lo = exact residual, re-rounded)
__device__ __forceinline__ void split2(float a, float b, unsigned &H, unsigned &L) {
    H = cvt_pk_bf16(a, b);
    const float ha = __uint_as_float(H << 16);
    const float hb = __uint_as_float(H & 0xFFFF0000u);
    L = cvt_pk_bf16(a - ha, b - hb);
}
__device__ __forceinline__ f32x4 MFMA(bf16x8 a, bf16x8 b, f32x4 c) {
    return __builtin_amdgcn_mfma_f32_16x16x32_bf16(a, b, c, 0, 0, 0);
}
// Non-temporal 16B load/store on ext_vector types (clang vector => builtin ok)
__device__ __forceinline__ f32x4 ntload4(const float* p) {
    return __builtin_nontemporal_load((const f32x4*)p);
}
__device__ __forceinline__ void ntstore4(float* p, f32x4 v) {
    __builtin_nontemporal_store(v, (f32x4*)p);
}

// ---------------------------------------------------------------------------
// Pack weights into MFMA fragment order (hi/lo bf16). 257 wgs: wg (blk*4+q)
// packs quarter q of 64x64 block blk; wg 256 builds the fixup/param table.
// blk 0..15 = R[b], 16..31 = L[c], 32..47 = Wd' = diag(gamma)Wd, 48..63 = Wu.
// Table at float offset (64*8192 ushorts): bcf[0..63]=B=gamma@Wd,
// bcf[64..127]=C=beta@Wd, bcf[128+p*8+{0..7}] = {gamma,beta,th0',th1',th2',
// ph0',ph1',ph2'} with th'/ph' pre-multiplied by 1/(2*pi).
// Frag addressing (ushorts): blk*8192 + ((kk*4+nt)*2+comp)*512 + lane*8
// element v of lane l:  M[kk*32 + (l>>4)*8 + v][nt*16 + (l&15)]
// ---------------------------------------------------------------------------
__global__ __launch_bounds__(256) void pack_weights(
    const float* __restrict__ R, const float* __restrict__ L,
    const float* __restrict__ Wd, const float* __restrict__ Wu,
    const float* __restrict__ gamma, const float* __restrict__ beta,
    const float* __restrict__ thetas, const float* __restrict__ phis,
    unsigned short* __restrict__ wsp)
{
    const int bx = blockIdx.x;
    const int tid = threadIdx.x;
    if (bx == 256) {
        float* bc = (float*)(wsp + (size_t)64 * 8192);
        const float INV2PI = 0.15915494309189535f;
        for (int i = tid; i < 1024; i += 256) {
            float* t = bc + 128 + i * 8;
            t[0] = gamma[i];                 t[1] = beta[i];
            t[2] = thetas[i] * INV2PI;       t[3] = thetas[1024 + i] * INV2PI;
            t[4] = thetas[2048 + i] * INV2PI;
            t[5] = phis[i] * INV2PI;         t[6] = phis[1024 + i] * INV2PI;
            t[7] = phis[2048 + i] * INV2PI;
        }
        __shared__ float red[8][64];
        const int r = tid & 63, part = tid >> 6;
        float sb = 0.f, sc = 0.f;
        for (int c = part * 256; c < part * 256 + 256; ++c) {
            const float w = Wd[(size_t)c * 64 + r];
            sb += gamma[c] * w;
            sc += beta[c] * w;
        }
        red[part][r] = sb; red[part + 4][r] = sc;
        __syncthreads();
        if (part == 0) {
            bc[r]      = red[0][r] + red[1][r] + red[2][r] + red[3][r];
            bc[64 + r] = red[4][r] + red[5][r] + red[6][r] + red[7][r];
        }
        return;
    }
    const int blk = bx >> 2;
    unsigned short* dst = wsp + (size_t)blk * 8192;
    const int slot = tid + (bx & 3) * 256;     // 0..1023
    const int fragidx = slot >> 6;             // 0..15
    const int l = slot & 63;
    const int kk = fragidx >> 3;
    const int nt = (fragidx >> 1) & 3;
    const int comp = fragidx & 1;
    const int g = l >> 4, r16 = l & 15;
    const int j = nt * 16 + r16;
    bf16x8 s;
    #pragma unroll
    for (int v = 0; v < 8; ++v) {
        const int k = kk * 32 + g * 8 + v;
        float w;
        if (blk < 16)      w = R[(size_t)blk * 4096 + k * 64 + j];
        else if (blk < 32) w = L[(size_t)(blk - 16) * 4096 + k * 64 + j];
        else if (blk < 48) {
            const int kglob = (blk - 32) * 64 + k;
            w = gamma[kglob] * Wd[(size_t)kglob * 64 + j];
        } else             w = Wu[(size_t)k * 1024 + (blk - 48) * 64 + j];
        unsigned short hi = f2bf(w);
        unsigned short bits = (comp == 0) ? hi : f2bf(w - bf2f(hi));
        s[v] = (short)bits;
    }
    *(bf16x8*)(dst + fragidx * 512 + l * 8) = s;
}

// ---------------------------------------------------------------------------
// Fused main kernel. 512 threads (8 waves), 16 tokens per workgroup.
// Wave w: grp = w>>2 (splits block/K loops), ntw = w&3 (16-col subtile).
// ---------------------------------------------------------------------------
__global__ __launch_bounds__(512, 4) void qrun_main(
    const float* __restrict__ x, const float* __restrict__ bias,
    const float* __restrict__ Wp, const float* __restrict__ bpv,
    const unsigned short* __restrict__ wpk, float* __restrict__ out)
{
    extern __shared__ char smem[];
    unsigned short* hiP = (unsigned short*)smem;          // [16][PITCH]
    unsigned short* loP = hiP + 16 * PITCH;               // [16][PITCH]
    float* dbuf = (float*)(loP + 16 * PITCH);             // [2][16][DPITCH]
    float* lnpart = dbuf + 2 * DHALF;                     // [8][16][2]
    float* statsR = lnpart + 256;                         // [16][2]

    const int tid = threadIdx.x;
    const int wave = tid >> 6, lane = tid & 63;
    const int g = lane >> 4, r16 = lane & 15;
    const int grp = wave >> 2, ntw = wave & 3;
    const size_t n0 = (size_t)blockIdx.x * 16;
    const int rowA = r16 * PITCH;

    // ---- phase 0: load x tile (non-temporal), split to hi/lo bf16 planes ----
    {
        const float* xb = x + n0 * 1024;
        #pragma unroll
        for (int it = 0; it < 4; ++it) {
            const int base = (it * 512 + tid) * 8;
            const int row = base >> 10, col = base & 1023;
            const f32x4 f0 = ntload4(xb + base);
            const f32x4 f1 = ntload4(xb + base + 4);
            unsigned H0, L0, H1, L1, H2, L2, H3, L3;
            split2(f0[0], f0[1], H0, L0);
            split2(f0[2], f0[3], H1, L1);
            split2(f1[0], f1[1], H2, L2);
            split2(f1[2], f1[3], H3, L3);
            *(uint4*)(hiP + row * PITCH + col) = make_uint4(H0, H1, H2, H3);
            *(uint4*)(loP + row * PITCH + col) = make_uint4(L0, L1, L2, L3);
        }
    }
    __syncthreads();

    // ---- phase 1: monarch stage 1 (x @ R[b]); reads all -> barrier -> writes ----
    f32x4 acc1[8];
    #pragma unroll
    for (int bi = 0; bi < 8; ++bi) {
        const int b = grp * 8 + bi;
        const unsigned short* wb = wpk + (size_t)b * 8192;
        bf16x8 Bh0 = *(const bf16x8*)(wb + ((0*4+ntw)*2+0)*512 + lane*8);
        bf16x8 Bl0 = *(const bf16x8*)(wb + ((0*4+ntw)*2+1)*512 + lane*8);
        bf16x8 Bh1 = *(const bf16x8*)(wb + ((1*4+ntw)*2+0)*512 + lane*8);
        bf16x8 Bl1 = *(const bf16x8*)(wb + ((1*4+ntw)*2+1)*512 + lane*8);
        const int ca = b * 64 + g * 8;
        bf16x8 Ah0 = *(const bf16x8*)(hiP + rowA + ca);
        bf16x8 Al0 = *(const bf16x8*)(loP + rowA + ca);
        bf16x8 Ah1 = *(const bf16x8*)(hiP + rowA + ca + 32);
        bf16x8 Al1 = *(const bf16x8*)(loP + rowA + ca + 32);
        f32x4 a = {0.f, 0.f, 0.f, 0.f};
        a = MFMA(Ah0, Bh0, a); a = MFMA(Ah0, Bl0, a); a = MFMA(Al0, Bh0, a);
        a = MFMA(Ah1, Bh1, a); a = MFMA(Ah1, Bl1, a); a = MFMA(Al1, Bh1, a);
        acc1[bi] = a;
    }
    __syncthreads();   // all stage-1 reads complete before permuted overwrite

    // permuted write: D col (b*64+ntw*16+r16) -> dest col; the 8 bi land on 8
    // consecutive columns => uint4 write. g-field XOR-swizzled by (c'&3).
    {
        const int Cw = (ntw * 4 + (r16 >> 2)) * 64 + ((r16 >> 1) & 1) * 32
                     + (((grp + 2 * (r16 & 1)) ^ (r16 >> 2)) << 3);
        #pragma unroll
        for (int v = 0; v < 4; ++v) {
            const int rowv = (g * 4 + v) * PITCH;
            unsigned h0, l0, h1, l1, h2, l2, h3, l3;
            split2(acc1[0][v], acc1[1][v], h0, l0);
            split2(acc1[2][v], acc1[3][v], h1, l1);
            split2(acc1[4][v], acc1[5][v], h2, l2);
            split2(acc1[6][v], acc1[7][v], h3, l3);
            *(uint4*)(hiP + rowv + Cw) = make_uint4(h0, h1, h2, h3);
            *(uint4*)(loP + rowv + Cw) = make_uint4(l0, l1, l2, l3);
        }
    }
    __syncthreads();

    // ---- phase 2: monarch stage 2, operand-swapped: h2^T = L^T @ mid^T ----
    f32x4 acc2[8];
    #pragma unroll
    for (int ci = 0; ci < 8; ++ci) {
        const int c = grp * 8 + ci;
        const unsigned short* wb = wpk + (size_t)(16 + c) * 8192;
        bf16x8 Wh0 = *(const bf16x8*)(wb + ((0*4+ntw)*2+0)*512 + lane*8);
        bf16x8 Wl0 = *(const bf16x8*)(wb + ((0*4+ntw)*2+1)*512 + lane*8);
        bf16x8 Wh1 = *(const bf16x8*)(wb + ((1*4+ntw)*2+0)*512 + lane*8);
        bf16x8 Wl1 = *(const bf16x8*)(wb + ((1*4+ntw)*2+1)*512 + lane*8);
        const int gx = ((g ^ (c & 3)) << 3);               // XOR swizzle (read)
        const int c0 = rowA + c * 64 + gx;                 // kk=0
        bf16x8 Hh0 = *(const bf16x8*)(hiP + c0);
        bf16x8 Hl0 = *(const bf16x8*)(loP + c0);
        bf16x8 Hh1 = *(const bf16x8*)(hiP + c0 + 32);
        bf16x8 Hl1 = *(const bf16x8*)(loP + c0 + 32);
        f32x4 a = {0.f, 0.f, 0.f, 0.f};
        a = MFMA(Wh0, Hh0, a); a = MFMA(Wh0, Hl0, a); a = MFMA(Wl0, Hh0, a);
        a = MFMA(Wh1, Hh1, a); a = MFMA(Wh1, Hl1, a); a = MFMA(Wl1, Hh1, a);
        acc2[ci] = a;
    }
    __syncthreads();   // all permuted-tile reads complete before overwrite

    // epilogue: +bias, write RAW h (hi/lo), LN partial sums
    {
        float s = 0.f, s2 = 0.f;
        #pragma unroll
        for (int ci = 0; ci < 8; ++ci) {
            const int c = grp * 8 + ci;
            const int ncol = c * 64 + ntw * 16 + g * 4;
            const float4 bv = *(const float4*)(bias + ncol);
            const float f0 = acc2[ci][0] + bv.x;
            const float f1 = acc2[ci][1] + bv.y;
            const float f2 = acc2[ci][2] + bv.z;
            const float f3 = acc2[ci][3] + bv.w;
            s += f0 + f1 + f2 + f3;
            s2 += f0 * f0 + f1 * f1 + f2 * f2 + f3 * f3;
            unsigned hA, lA, hB, lB;
            split2(f0, f1, hA, lA);
            split2(f2, f3, hB, lB);
            *(uint2*)(hiP + rowA + ncol) = make_uint2(hA, hB);
            *(uint2*)(loP + rowA + ncol) = make_uint2(lA, lB);
        }
        s  += __shfl_xor(s, 16);  s  += __shfl_xor(s, 32);
        s2 += __shfl_xor(s2, 16); s2 += __shfl_xor(s2, 32);
        if (g == 0) {
            lnpart[(wave * 16 + r16) * 2]     = s;
            lnpart[(wave * 16 + r16) * 2 + 1] = s2;
        }
    }
    __syncthreads();

    // ---- phase 4: down-proj on RAW h, swapped: d^T = Wd'^T @ h^T (hi-only);
    //      first 16 lanes also finish the LN stats reduce.
    if (tid < 16) {
        float s = 0.f, s2 = 0.f;
        #pragma unroll
        for (int w = 0; w < 8; ++w) {
            s  += lnpart[(w * 16 + tid) * 2];
            s2 += lnpart[(w * 16 + tid) * 2 + 1];
        }
        const float mu = s * (1.f / 1024.f);
        statsR[tid * 2]     = mu;
        statsR[tid * 2 + 1] = rsqrtf(s2 * (1.f / 1024.f) - mu * mu + 1e-5f);
    }
    {
        f32x4 accd = {0.f, 0.f, 0.f, 0.f};
        #pragma unroll
        for (int ki = 0; ki < 16; ++ki) {
            const int kq = grp * 16 + ki;
            const int kb = kq >> 1, kin = kq & 1;
            const unsigned short* wb = wpk + (size_t)(32 + kb) * 8192;
            bf16x8 Wh = *(const bf16x8*)(wb + ((kin*4+ntw)*2+0)*512 + lane*8);
            bf16x8 Hh = *(const bf16x8*)(hiP + rowA + kq * 32 + g * 8);
            accd = MFMA(Wh, Hh, accd);
        }
        // D[rank-local g*4+v][token r16]; rank r = ntw*16 + g*4 + v
        *(f32x4*)(dbuf + grp * DHALF + r16 * DPITCH + ntw * 16 + g * 4) = accd;
    }
    __syncthreads();

    // ---- phase 5: LN-fixup + up-proj + residual + sin/cos + final linear ----
    const float* bcf = (const float*)(wpk + (size_t)64 * 8192);
    const float muT = statsR[r16 * 2], rsT = statsR[r16 * 2 + 1];
    float muR[4], rsR[4];
    #pragma unroll
    for (int v = 0; v < 4; ++v) {
        muR[v] = statsR[(g * 4 + v) * 2];
        rsR[v] = statsR[(g * 4 + v) * 2 + 1];
    }
    bf16x8 dA[2];
    #pragma unroll
    for (int kk = 0; kk < 2; ++kk) {
        const int rb = kk * 32 + g * 8;
        const float4 B0 = *(const float4*)(bcf + rb);
        const float4 B1 = *(const float4*)(bcf + rb + 4);
        const float4 C0 = *(const float4*)(bcf + 64 + rb);
        const float4 C1 = *(const float4*)(bcf + 64 + rb + 4);
        const float Ba[8] = {B0.x,B0.y,B0.z,B0.w,B1.x,B1.y,B1.z,B1.w};
        const float Ca[8] = {C0.x,C0.y,C0.z,C0.w,C1.x,C1.y,C1.z,C1.w};
        const int di = r16 * DPITCH + rb;
        const f32x4 q0 = *(const f32x4*)(dbuf + di);
        const f32x4 q1 = *(const f32x4*)(dbuf + di + 4);
        const f32x4 p0 = *(const f32x4*)(dbuf + DHALF + di);
        const f32x4 p1 = *(const f32x4*)(dbuf + DHALF + di + 4);
        float dv[8];
        #pragma unroll
        for (int v = 0; v < 4; ++v) {
            dv[v]     = rsT * (q0[v] + p0[v]) - muT * rsT * Ba[v]     + Ca[v];
            dv[v + 4] = rsT * (q1[v] + p1[v]) - muT * rsT * Ba[v + 4] + Ca[v + 4];
        }
        const uint4 uu = make_uint4(cvt_pk_bf16(dv[0], dv[1]),
                                    cvt_pk_bf16(dv[2], dv[3]),
                                    cvt_pk_bf16(dv[4], dv[5]),
                                    cvt_pk_bf16(dv[6], dv[7]));
        dA[kk] = __builtin_bit_cast(bf16x8, uu);
    }
    float wp[24];
    #pragma unroll
    for (int k2 = 0; k2 < 24; ++k2) wp[k2] = Wp[k2];
    const float bp0 = bpv[0], bp1 = bpv[1], bp2 = bpv[2], bp3 = bpv[3];

    #pragma unroll 1
    for (int j = 0; j < 8; ++j) {
        const int ntg = wave * 8 + j;
        const int nb = ntg >> 2, ntin = ntg & 3;
        const unsigned short* wb = wpk + (size_t)(48 + nb) * 8192;
        bf16x8 Bh0 = *(const bf16x8*)(wb + ((0*4+ntin)*2+0)*512 + lane*8);
        bf16x8 Bh1 = *(const bf16x8*)(wb + ((1*4+ntin)*2+0)*512 + lane*8);
        f32x4 au = {0.f, 0.f, 0.f, 0.f};
        au = MFMA(dA[0], Bh0, au);
        au = MFMA(dA[1], Bh1, au);
        const int p = ntg * 16 + r16;
        const float4 t0 = *(const float4*)(bcf + 128 + p * 8);
        const float4 t1 = *(const float4*)(bcf + 128 + p * 8 + 4);
        const float gp = t0.x, bpp = t0.y;
        const float th0 = t0.z, th1 = t0.w, th2 = t1.x;
        const float ph0 = t1.y, ph1 = t1.z, ph2 = t1.w;
        #pragma unroll
        for (int v = 0; v < 4; ++v) {
            const int row = g * 4 + v;
            const float hraw = bf2f(hiP[row * PITCH + p]) + bf2f(loP[row * PITCH + p]);
            const float hn = (hraw - muR[v]) * rsR[v] * gp + bpp;
            const float e = au[v] + hn;
            float o0 = bp0, o1 = bp1, o2 = bp2, o3 = bp3;
            float arg, sn, cs;
            asm("v_fract_f32 %0, %1" : "=v"(arg) : "v"(fmaf(e, th0, ph0)));
            asm("v_sin_f32 %0, %1" : "=v"(sn) : "v"(arg));
            asm("v_cos_f32 %0, %1" : "=v"(cs) : "v"(arg));
            o0 = fmaf(sn, wp[0],  fmaf(cs, wp[1],  o0));
            o1 = fmaf(sn, wp[6],  fmaf(cs, wp[7],  o1));
            o2 = fmaf(sn, wp[12], fmaf(cs, wp[13], o2));
            o3 = fmaf(sn, wp[18], fmaf(cs, wp[19], o3));
            asm("v_fract_f32 %0, %1" : "=v"(arg) : "v"(fmaf(e, th1, ph1)));
            asm("v_sin_f32 %0, %1" : "=v"(sn) : "v"(arg));
            asm("v_cos_f32 %0, %1" : "=v"(cs) : "v"(arg));
            o0 = fmaf(sn, wp[2],  fmaf(cs, wp[3],  o0));
            o1 = fmaf(sn, wp[8],  fmaf(cs, wp[9],  o1));
            o2 = fmaf(sn, wp[14], fmaf(cs, wp[15], o2));
            o3 = fmaf(sn, wp[20], fmaf(cs, wp[21], o3));
            asm("v_fract_f32 %0, %1" : "=v"(arg) : "v"(fmaf(e, th2, ph2)));
            asm("v_sin_f32 %0, %1" : "=v"(sn) : "v"(arg));
            asm("v_cos_f32 %0, %1" : "=v"(cs) : "v"(arg));
            o0 = fmaf(sn, wp[4],  fmaf(cs, wp[5],  o0));
            o1 = fmaf(sn, wp[10], fmaf(cs, wp[11], o1));
            o2 = fmaf(sn, wp[16], fmaf(cs, wp[17], o2));
            o3 = fmaf(sn, wp[22], fmaf(cs, wp[23], o3));
            f32x4 ov = {o0, o1, o2, o3};
            ntstore4(out + ((n0 + row) * 1024 + p) * 4, ov);
        }
    }
}

extern "C" void kernel_launch(void* const* d_in, const int* in_sizes, int n_in,
                              void* d_out, int out_size, void* d_ws, size_t ws_size,
                              hipStream_t stream) {
    const float* x      = (const float*)d_in[0];
    const float* R      = (const float*)d_in[1];
    const float* L      = (const float*)d_in[2];
    const float* bias   = (const float*)d_in[3];
    const float* gamma  = (const float*)d_in[4];
    const float* beta   = (const float*)d_in[5];
    const float* Wd     = (const float*)d_in[6];
    const float* Wu     = (const float*)d_in[7];
    const float* thetas = (const float*)d_in[8];
    const float* phis   = (const float*)d_in[9];
    const float* Wp     = (const float*)d_in[10];
    const float* bp     = (const float*)d_in[11];
    float* out = (float*)d_out;
    unsigned short* wsp = (unsigned short*)d_ws;
    const int N = in_sizes[0] / 1024;   // 8192 tokens

    (void)hipFuncSetAttribute((const void*)qrun_main,
                              hipFuncAttributeMaxDynamicSharedMemorySize, SMEM_BYTES);
    pack_weights<<<dim3(257), dim3(256), 0, stream>>>(R, L, Wd, Wu, gamma, beta,
                                                      thetas, phis, wsp);
    qrun_main<<<dim3(N / 16), dim3(512), SMEM_BYTES, stream>>>(
        x, bias, Wp, bp, wsp, out);
}

// Round 13
// 52.800 us; speedup vs baseline: 1.4779x; 1.1011x over previous
//
#include <hip/hip_runtime.h>

// Q_RUNLayer_Hybrid: monarch(blockdiag R -> stride perm -> blockdiag L) + bias
// -> LayerNorm -> h + (h@Wd)@Wu -> sin/cos reupload (3) -> [PROJ,6]@Wp.T+bp
// R13 = R12 (nt x-loads/out-stores, 16 tok/wg, 512 thr, 2 wg/CU) with the
// monarch WEIGHT-lo MFMAs dropped: S1/S2 use R/L hi-frags only (4 MFMA per
// block-step instead of 6; Bl/Wl frag loads eliminated -> weight L2 traffic
// -32%). x-split and mid-split stay exact, so added error is only the
// 2^-9-relative weight rounding (~+5e-3 absmax vs 2.6e-2 threshold).
// Split-bf16 via v_cvt_pk_bf16_f32; LayerNorm folded into down-proj
// (Wd' = diag(gamma)Wd; fixup B=gamma@Wd, C=beta@Wd); packed per-p param
// table with 1/(2pi)-folded thetas/phis for v_fract/v_sin/v_cos.
// NOTE: direct-global-x in S1 is RETIRED (R5+R11 both fail ~0.95 absmax).

typedef __attribute__((ext_vector_type(8))) short bf16x8;
typedef __attribute__((ext_vector_type(4))) float f32x4;

#define PITCH 1032            // ushorts per plane row (1024 + 8 pad)
#define DPITCH 68             // floats per dbuf row
#define DHALF (16 * DPITCH)   // 1088
#define SMEM_BYTES 75904      // 2*16*1032*2 + 2*1088*4 + 256*4 + 32*4

__device__ __forceinline__ unsigned short f2bf(float f) {
    unsigned u = __float_as_uint(f);
    u = (u + 0x7FFFu + ((u >> 16) & 1u)) >> 16;   // RNE f32 -> bf16
    return (unsigned short)u;
}
__device__ __forceinline__ float bf2f(unsigned short h) {
    return __uint_as_float(((unsigned)h) << 16);
}
__device__ __forceinline__ unsigned cvt_pk_bf16(float a, float b) {
    unsigned r;                                   // lo16 = bf16(a), hi16 = bf16(b)
    asm("v_cvt_pk_bf16_f32 %0, %1, %2" : "=v"(r) : "v"(a), "v"(b));
    return r;
}
// split (a,b) -> packed hi u32 + packed lo u32 (lo = exact residual, re-rounded)
__device__ __forceinline__ void split2(float a, float b, unsigned &H, unsigned &L) {
    H = cvt_pk_bf16(a, b);
    const float ha = __uint_as_float(H << 16);
    const float hb = __uint_as_float(H & 0xFFFF0000u);
    L = cvt_pk_bf16(a - ha, b - hb);
}
__device__ __forceinline__ f32x4 MFMA(bf16x8 a, bf16x8 b, f32x4 c) {
    return __builtin_amdgcn_mfma_f32_16x16x32_bf16(a, b, c, 0, 0, 0);
}
// Non-temporal 16B load/store (streaming data: keep L2 for the weight set)
__device__ __forceinline__ f32x4 ntload4(const float* p) {
    return __builtin_nontemporal_load((const f32x4*)p);
}
__device__ __forceinline__ void ntstore4(float* p, f32x4 v) {
    __builtin_nontemporal_store(v, (f32x4*)p);
}

// ---------------------------------------------------------------------------
// Pack weights into MFMA fragment order (hi/lo bf16). 257 wgs: wg (blk*4+q)
// packs quarter q of 64x64 block blk; wg 256 builds the fixup/param table.
// blk 0..15 = R[b], 16..31 = L[c], 32..47 = Wd' = diag(gamma)Wd, 48..63 = Wu.
// Table at float offset (64*8192 ushorts): bcf[0..63]=B=gamma@Wd,
// bcf[64..127]=C=beta@Wd, bcf[128+p*8+{0..7}] = {gamma,beta,th0',th1',th2',
// ph0',ph1',ph2'} with th'/ph' pre-multiplied by 1/(2*pi).
// Frag addressing (ushorts): blk*8192 + ((kk*4+nt)*2+comp)*512 + lane*8
// element v of lane l:  M[kk*32 + (l>>4)*8 + v][nt*16 + (l&15)]
// (lo frags of R/L/Wd/Wu are still packed for layout stability; R13's main
//  kernel no longer reads the R/L lo frags.)
// ---------------------------------------------------------------------------
__global__ __launch_bounds__(256) void pack_weights(
    const float* __restrict__ R, const float* __restrict__ L,
    const float* __restrict__ Wd, const float* __restrict__ Wu,
    const float* __restrict__ gamma, const float* __restrict__ beta,
    const float* __restrict__ thetas, const float* __restrict__ phis,
    unsigned short* __restrict__ wsp)
{
    const int bx = blockIdx.x;
    const int tid = threadIdx.x;
    if (bx == 256) {
        float* bc = (float*)(wsp + (size_t)64 * 8192);
        const float INV2PI = 0.15915494309189535f;
        for (int i = tid; i < 1024; i += 256) {
            float* t = bc + 128 + i * 8;
            t[0] = gamma[i];                 t[1] = beta[i];
            t[2] = thetas[i] * INV2PI;       t[3] = thetas[1024 + i] * INV2PI;
            t[4] = thetas[2048 + i] * INV2PI;
            t[5] = phis[i] * INV2PI;         t[6] = phis[1024 + i] * INV2PI;
            t[7] = phis[2048 + i] * INV2PI;
        }
        __shared__ float red[8][64];
        const int r = tid & 63, part = tid >> 6;
        float sb = 0.f, sc = 0.f;
        for (int c = part * 256; c < part * 256 + 256; ++c) {
            const float w = Wd[(size_t)c * 64 + r];
            sb += gamma[c] * w;
            sc += beta[c] * w;
        }
        red[part][r] = sb; red[part + 4][r] = sc;
        __syncthreads();
        if (part == 0) {
            bc[r]      = red[0][r] + red[1][r] + red[2][r] + red[3][r];
            bc[64 + r] = red[4][r] + red[5][r] + red[6][r] + red[7][r];
        }
        return;
    }
    const int blk = bx >> 2;
    unsigned short* dst = wsp + (size_t)blk * 8192;
    const int slot = tid + (bx & 3) * 256;     // 0..1023
    const int fragidx = slot >> 6;             // 0..15
    const int l = slot & 63;
    const int kk = fragidx >> 3;
    const int nt = (fragidx >> 1) & 3;
    const int comp = fragidx & 1;
    const int g = l >> 4, r16 = l & 15;
    const int j = nt * 16 + r16;
    bf16x8 s;
    #pragma unroll
    for (int v = 0; v < 8; ++v) {
        const int k = kk * 32 + g * 8 + v;
        float w;
        if (blk < 16)      w = R[(size_t)blk * 4096 + k * 64 + j];
        else if (blk < 32) w = L[(size_t)(blk - 16) * 4096 + k * 64 + j];
        else if (blk < 48) {
            const int kglob = (blk - 32) * 64 + k;
            w = gamma[kglob] * Wd[(size_t)kglob * 64 + j];
        } else             w = Wu[(size_t)k * 1024 + (blk - 48) * 64 + j];
        unsigned short hi = f2bf(w);
        unsigned short bits = (comp == 0) ? hi : f2bf(w - bf2f(hi));
        s[v] = (short)bits;
    }
    *(bf16x8*)(dst + fragidx * 512 + l * 8) = s;
}

// ---------------------------------------------------------------------------
// Fused main kernel. 512 threads (8 waves), 16 tokens per workgroup.
// Wave w: grp = w>>2 (splits block/K loops), ntw = w&3 (16-col subtile).
// ---------------------------------------------------------------------------
__global__ __launch_bounds__(512, 4) void qrun_main(
    const float* __restrict__ x, const float* __restrict__ bias,
    const float* __restrict__ Wp, const float* __restrict__ bpv,
    const unsigned short* __restrict__ wpk, float* __restrict__ out)
{
    extern __shared__ char smem[];
    unsigned short* hiP = (unsigned short*)smem;          // [16][PITCH]
    unsigned short* loP = hiP + 16 * PITCH;               // [16][PITCH]
    float* dbuf = (float*)(loP + 16 * PITCH);             // [2][16][DPITCH]
    float* lnpart = dbuf + 2 * DHALF;                     // [8][16][2]
    float* statsR = lnpart + 256;                         // [16][2]

    const int tid = threadIdx.x;
    const int wave = tid >> 6, lane = tid & 63;
    const int g = lane >> 4, r16 = lane & 15;
    const int grp = wave >> 2, ntw = wave & 3;
    const size_t n0 = (size_t)blockIdx.x * 16;
    const int rowA = r16 * PITCH;

    // ---- phase 0: load x tile (non-temporal), split to hi/lo bf16 planes ----
    {
        const float* xb = x + n0 * 1024;
        #pragma unroll
        for (int it = 0; it < 4; ++it) {
            const int base = (it * 512 + tid) * 8;
            const int row = base >> 10, col = base & 1023;
            const f32x4 f0 = ntload4(xb + base);
            const f32x4 f1 = ntload4(xb + base + 4);
            unsigned H0, L0, H1, L1, H2, L2, H3, L3;
            split2(f0[0], f0[1], H0, L0);
            split2(f0[2], f0[3], H1, L1);
            split2(f1[0], f1[1], H2, L2);
            split2(f1[2], f1[3], H3, L3);
            *(uint4*)(hiP + row * PITCH + col) = make_uint4(H0, H1, H2, H3);
            *(uint4*)(loP + row * PITCH + col) = make_uint4(L0, L1, L2, L3);
        }
    }
    __syncthreads();

    // ---- phase 1: monarch stage 1 (x @ Rhi[b]); x-split exact, weight hi-only ----
    f32x4 acc1[8];
    #pragma unroll
    for (int bi = 0; bi < 8; ++bi) {
        const int b = grp * 8 + bi;
        const unsigned short* wb = wpk + (size_t)b * 8192;
        bf16x8 Bh0 = *(const bf16x8*)(wb + ((0*4+ntw)*2+0)*512 + lane*8);
        bf16x8 Bh1 = *(const bf16x8*)(wb + ((1*4+ntw)*2+0)*512 + lane*8);
        const int ca = b * 64 + g * 8;
        bf16x8 Ah0 = *(const bf16x8*)(hiP + rowA + ca);
        bf16x8 Al0 = *(const bf16x8*)(loP + rowA + ca);
        bf16x8 Ah1 = *(const bf16x8*)(hiP + rowA + ca + 32);
        bf16x8 Al1 = *(const bf16x8*)(loP + rowA + ca + 32);
        f32x4 a = {0.f, 0.f, 0.f, 0.f};
        a = MFMA(Ah0, Bh0, a); a = MFMA(Al0, Bh0, a);
        a = MFMA(Ah1, Bh1, a); a = MFMA(Al1, Bh1, a);
        acc1[bi] = a;
    }
    __syncthreads();   // all stage-1 reads complete before permuted overwrite

    // permuted write: D col (b*64+ntw*16+r16) -> dest col; the 8 bi land on 8
    // consecutive columns => uint4 write. g-field XOR-swizzled by (c'&3).
    {
        const int Cw = (ntw * 4 + (r16 >> 2)) * 64 + ((r16 >> 1) & 1) * 32
                     + (((grp + 2 * (r16 & 1)) ^ (r16 >> 2)) << 3);
        #pragma unroll
        for (int v = 0; v < 4; ++v) {
            const int rowv = (g * 4 + v) * PITCH;
            unsigned h0, l0, h1, l1, h2, l2, h3, l3;
            split2(acc1[0][v], acc1[1][v], h0, l0);
            split2(acc1[2][v], acc1[3][v], h1, l1);
            split2(acc1[4][v], acc1[5][v], h2, l2);
            split2(acc1[6][v], acc1[7][v], h3, l3);
            *(uint4*)(hiP + rowv + Cw) = make_uint4(h0, h1, h2, h3);
            *(uint4*)(loP + rowv + Cw) = make_uint4(l0, l1, l2, l3);
        }
    }
    __syncthreads();

    // ---- phase 2: monarch stage 2 swapped: h2^T = Lhi^T @ mid^T (mid split) ----
    f32x4 acc2[8];
    #pragma unroll
    for (int ci = 0; ci < 8; ++ci) {
        const int c = grp * 8 + ci;
        const unsigned short* wb = wpk + (size_t)(16 + c) * 8192;
        bf16x8 Wh0 = *(const bf16x8*)(wb + ((0*4+ntw)*2+0)*512 + lane*8);
        bf16x8 Wh1 = *(const bf16x8*)(wb + ((1*4+ntw)*2+0)*512 + lane*8);
        const int gx = ((g ^ (c & 3)) << 3);               // XOR swizzle (read)
        const int c0 = rowA + c * 64 + gx;                 // kk=0
        bf16x8 Hh0 = *(const bf16x8*)(hiP + c0);
        bf16x8 Hl0 = *(const bf16x8*)(loP + c0);
        bf16x8 Hh1 = *(const bf16x8*)(hiP + c0 + 32);
        bf16x8 Hl1 = *(const bf16x8*)(loP + c0 + 32);
        f32x4 a = {0.f, 0.f, 0.f, 0.f};
        a = MFMA(Wh0, Hh0, a); a = MFMA(Wh0, Hl0, a);
        a = MFMA(Wh1, Hh1, a); a = MFMA(Wh1, Hl1, a);
        acc2[ci] = a;
    }
    __syncthreads();   // all permuted-tile reads complete before overwrite

    // epilogue: +bias, write RAW h (hi/lo), LN partial sums
    {
        float s = 0.f, s2 = 0.f;
        #pragma unroll
        for (int ci = 0; ci < 8; ++ci) {
            const int c = grp * 8 + ci;
            const int ncol = c * 64 + ntw * 16 + g * 4;
            const float4 bv = *(const float4*)(bias + ncol);
            const float f0 = acc2[ci][0] + bv.x;
            const float f1 = acc2[ci][1] + bv.y;
            const float f2 = acc2[ci][2] + bv.z;
            const float f3 = acc2[ci][3] + bv.w;
            s += f0 + f1 + f2 + f3;
            s2 += f0 * f0 + f1 * f1 + f2 * f2 + f3 * f3;
            unsigned hA, lA, hB, lB;
            split2(f0, f1, hA, lA);
            split2(f2, f3, hB, lB);
            *(uint2*)(hiP + rowA + ncol) = make_uint2(hA, hB);
            *(uint2*)(loP + rowA + ncol) = make_uint2(lA, lB);
        }
        s  += __shfl_xor(s, 16);  s  += __shfl_xor(s, 32);
        s2 += __shfl_xor(s2, 16); s2 += __shfl_xor(s2, 32);
        if (g == 0) {
            lnpart[(wave * 16 + r16) * 2]     = s;
            lnpart[(wave * 16 + r16) * 2 + 1] = s2;
        }
    }
    __syncthreads();

    // ---- phase 4: down-proj on RAW h, swapped: d^T = Wd'^T @ h^T (hi-only);
    //      first 16 lanes also finish the LN stats reduce.
    if (tid < 16) {
        float s = 0.f, s2 = 0.f;
        #pragma unroll
        for (int w = 0; w < 8; ++w) {
            s  += lnpart[(w * 16 + tid) * 2];
            s2 += lnpart[(w * 16 + tid) * 2 + 1];
        }
        const float mu = s * (1.f / 1024.f);
        statsR[tid * 2]     = mu;
        statsR[tid * 2 + 1] = rsqrtf(s2 * (1.f / 1024.f) - mu * mu + 1e-5f);
    }
    {
        f32x4 accd = {0.f, 0.f, 0.f, 0.f};
        #pragma unroll
        for (int ki = 0; ki < 16; ++ki) {
            const int kq = grp * 16 + ki;
            const int kb = kq >> 1, kin = kq & 1;
            const unsigned short* wb = wpk + (size_t)(32 + kb) * 8192;
            bf16x8 Wh = *(const bf16x8*)(wb + ((kin*4+ntw)*2+0)*512 + lane*8);
            bf16x8 Hh = *(const bf16x8*)(hiP + rowA + kq * 32 + g * 8);
            accd = MFMA(Wh, Hh, accd);
        }
        // D[rank-local g*4+v][token r16]; rank r = ntw*16 + g*4 + v
        *(f32x4*)(dbuf + grp * DHALF + r16 * DPITCH + ntw * 16 + g * 4) = accd;
    }
    __syncthreads();

    // ---- phase 5: LN-fixup + up-proj + residual + sin/cos + final linear ----
    const float* bcf = (const float*)(wpk + (size_t)64 * 8192);
    const float muT = statsR[r16 * 2], rsT = statsR[r16 * 2 + 1];
    float muR[4], rsR[4];
    #pragma unroll
    for (int v = 0; v < 4; ++v) {
        muR[v] = statsR[(g * 4 + v) * 2];
        rsR[v] = statsR[(g * 4 + v) * 2 + 1];
    }
    bf16x8 dA[2];
    #pragma unroll
    for (int kk = 0; kk < 2; ++kk) {
        const int rb = kk * 32 + g * 8;
        const float4 B0 = *(const float4*)(bcf + rb);
        const float4 B1 = *(const float4*)(bcf + rb + 4);
        const float4 C0 = *(const float4*)(bcf + 64 + rb);
        const float4 C1 = *(const float4*)(bcf + 64 + rb + 4);
        const float Ba[8] = {B0.x,B0.y,B0.z,B0.w,B1.x,B1.y,B1.z,B1.w};
        const float Ca[8] = {C0.x,C0.y,C0.z,C0.w,C1.x,C1.y,C1.z,C1.w};
        const int di = r16 * DPITCH + rb;
        const f32x4 q0 = *(const f32x4*)(dbuf + di);
        const f32x4 q1 = *(const f32x4*)(dbuf + di + 4);
        const f32x4 p0 = *(const f32x4*)(dbuf + DHALF + di);
        const f32x4 p1 = *(const f32x4*)(dbuf + DHALF + di + 4);
        float dv[8];
        #pragma unroll
        for (int v = 0; v < 4; ++v) {
            dv[v]     = rsT * (q0[v] + p0[v]) - muT * rsT * Ba[v]     + Ca[v];
            dv[v + 4] = rsT * (q1[v] + p1[v]) - muT * rsT * Ba[v + 4] + Ca[v + 4];
        }
        const uint4 uu = make_uint4(cvt_pk_bf16(dv[0], dv[1]),
                                    cvt_pk_bf16(dv[2], dv[3]),
                                    cvt_pk_bf16(dv[4], dv[5]),
                                    cvt_pk_bf16(dv[6], dv[7]));
        dA[kk] = __builtin_bit_cast(bf16x8, uu);
    }
    float wp[24];
    #pragma unroll
    for (int k2 = 0; k2 < 24; ++k2) wp[k2] = Wp[k2];
    const float bp0 = bpv[0], bp1 = bpv[1], bp2 = bpv[2], bp3 = bpv[3];

    #pragma unroll 1
    for (int j = 0; j < 8; ++j) {
        const int ntg = wave * 8 + j;
        const int nb = ntg >> 2, ntin = ntg & 3;
        const unsigned short* wb = wpk + (size_t)(48 + nb) * 8192;
        bf16x8 Bh0 = *(const bf16x8*)(wb + ((0*4+ntin)*2+0)*512 + lane*8);
        bf16x8 Bh1 = *(const bf16x8*)(wb + ((1*4+ntin)*2+0)*512 + lane*8);
        f32x4 au = {0.f, 0.f, 0.f, 0.f};
        au = MFMA(dA[0], Bh0, au);
        au = MFMA(dA[1], Bh1, au);
        const int p = ntg * 16 + r16;
        const float4 t0 = *(const float4*)(bcf + 128 + p * 8);
        const float4 t1 = *(const float4*)(bcf + 128 + p * 8 + 4);
        const float gp = t0.x, bpp = t0.y;
        const float th0 = t0.z, th1 = t0.w, th2 = t1.x;
        const float ph0 = t1.y, ph1 = t1.z, ph2 = t1.w;
        #pragma unroll
        for (int v = 0; v < 4; ++v) {
            const int row = g * 4 + v;
            const float hraw = bf2f(hiP[row * PITCH + p]) + bf2f(loP[row * PITCH + p]);
            const float hn = (hraw - muR[v]) * rsR[v] * gp + bpp;
            const float e = au[v] + hn;
            float o0 = bp0, o1 = bp1, o2 = bp2, o3 = bp3;
            float arg, sn, cs;
            asm("v_fract_f32 %0, %1" : "=v"(arg) : "v"(fmaf(e, th0, ph0)));
            asm("v_sin_f32 %0, %1" : "=v"(sn) : "v"(arg));
            asm("v_cos_f32 %0, %1" : "=v"(cs) : "v"(arg));
            o0 = fmaf(sn, wp[0],  fmaf(cs, wp[1],  o0));
            o1 = fmaf(sn, wp[6],  fmaf(cs, wp[7],  o1));
            o2 = fmaf(sn, wp[12], fmaf(cs, wp[13], o2));
            o3 = fmaf(sn, wp[18], fmaf(cs, wp[19], o3));
            asm("v_fract_f32 %0, %1" : "=v"(arg) : "v"(fmaf(e, th1, ph1)));
            asm("v_sin_f32 %0, %1" : "=v"(sn) : "v"(arg));
            asm("v_cos_f32 %0, %1" : "=v"(cs) : "v"(arg));
            o0 = fmaf(sn, wp[2],  fmaf(cs, wp[3],  o0));
            o1 = fmaf(sn, wp[8],  fmaf(cs, wp[9],  o1));
            o2 = fmaf(sn, wp[14], fmaf(cs, wp[15], o2));
            o3 = fmaf(sn, wp[20], fmaf(cs, wp[21], o3));
            asm("v_fract_f32 %0, %1" : "=v"(arg) : "v"(fmaf(e, th2, ph2)));
            asm("v_sin_f32 %0, %1" : "=v"(sn) : "v"(arg));
            asm("v_cos_f32 %0, %1" : "=v"(cs) : "v"(arg));
            o0 = fmaf(sn, wp[4],  fmaf(cs, wp[5],  o0));
            o1 = fmaf(sn, wp[10], fmaf(cs, wp[11], o1));
            o2 = fmaf(sn, wp[16], fmaf(cs, wp[17], o2));
            o3 = fmaf(sn, wp[22], fmaf(cs, wp[23], o3));
            f32x4 ov = {o0, o1, o2, o3};
            ntstore4(out + ((n0 + row) * 1024 + p) * 4, ov);
        }
    }
}

extern "C" void kernel_launch(void* const* d_in, const int* in_sizes, int n_in,
                              void* d_out, int out_size, void* d_ws, size_t ws_size,
                              hipStream_t stream) {
    const float* x      = (const float*)d_in[0];
    const float* R      = (const float*)d_in[1];
    const float* L      = (const float*)d_in[2];
    const float* bias   = (const float*)d_in[3];
    const float* gamma  = (const float*)d_in[4];
    const float* beta   = (const float*)d_in[5];
    const float* Wd     = (const float*)d_in[6];
    const float* Wu     = (const float*)d_in[7];
    const float* thetas = (const float*)d_in[8];
    const float* phis   = (const float*)d_in[9];
    const float* Wp     = (const float*)d_in[10];
    const float* bp     = (const float*)d_in[11];
    float* out = (float*)d_out;
    unsigned short* wsp = (unsigned short*)d_ws;
    const int N = in_sizes[0] / 1024;   // 8192 tokens

    (void)hipFuncSetAttribute((const void*)qrun_main,
                              hipFuncAttributeMaxDynamicSharedMemorySize, SMEM_BYTES);
    pack_weights<<<dim3(257), dim3(256), 0, stream>>>(R, L, Wd, Wu, gamma, beta,
                                                      thetas, phis, wsp);
    qrun_main<<<dim3(N / 16), dim3(512), SMEM_BYTES, stream>>>(
        x, bias, Wp, bp, wsp, out);
}

// Round 17
// 52.573 us; speedup vs baseline: 1.4842x; 1.0043x over previous
//
#include <hip/hip_runtime.h>

// Q_RUNLayer_Hybrid: monarch(blockdiag R -> stride perm -> blockdiag L) + bias
// -> LayerNorm -> h + (h@Wd)@Wu -> sin/cos reupload (3) -> [PROJ,6]@Wp.T+bp
// R17 = R13 qrun_main VERBATIM (green, 52.8us) + coalesced pack_weights:
// each block wg stages its 64x64 f32 weight block in LDS via coalesced
// float4 row loads (gamma applied at load for Wd'), then computes the
// IDENTICAL fragment bytes from LDS (bit-identical -> absmax must stay
// 0.01171875). Old pack did 524K scattered stride-64 gathers (~33MB cold
// cacheline traffic, 5-8us serial prologue).
// Hot-loop restructures are RETIRED (R5/R11/R15/R16 all fail inspection-clean).

typedef __attribute__((ext_vector_type(8))) short bf16x8;
typedef __attribute__((ext_vector_type(4))) float f32x4;

#define PITCH 1032            // ushorts per plane row (1024 + 8 pad)
#define DPITCH 68             // floats per dbuf row
#define DHALF (16 * DPITCH)   // 1088
#define SMEM_BYTES 59392      // qrun: 33024 + 16512 + 8704 + 1024 + 128  (R13 layout w/ lo plane)
#undef SMEM_BYTES
#define SMEM_BYTES 75904      // R13: 2*16*1032*2 + 2*1088*4 + 256*4 + 32*4

__device__ __forceinline__ unsigned short f2bf(float f) {
    unsigned u = __float_as_uint(f);
    u = (u + 0x7FFFu + ((u >> 16) & 1u)) >> 16;   // RNE f32 -> bf16
    return (unsigned short)u;
}
__device__ __forceinline__ float bf2f(unsigned short h) {
    return __uint_as_float(((unsigned)h) << 16);
}
__device__ __forceinline__ unsigned cvt_pk_bf16(float a, float b) {
    unsigned r;                                   // lo16 = bf16(a), hi16 = bf16(b)
    asm("v_cvt_pk_bf16_f32 %0, %1, %2" : "=v"(r) : "v"(a), "v"(b));
    return r;
}
// split (a,b) -> packed hi u32 + packed lo u32 (lo = exact residual, re-rounded)
__device__ __forceinline__ void split2(float a, float b, unsigned &H, unsigned &L) {
    H = cvt_pk_bf16(a, b);
    const float ha = __uint_as_float(H << 16);
    const float hb = __uint_as_float(H & 0xFFFF0000u);
    L = cvt_pk_bf16(a - ha, b - hb);
}
__device__ __forceinline__ f32x4 MFMA(bf16x8 a, bf16x8 b, f32x4 c) {
    return __builtin_amdgcn_mfma_f32_16x16x32_bf16(a, b, c, 0, 0, 0);
}
// Non-temporal 16B load/store (streaming data: keep L2 for the weight set)
__device__ __forceinline__ f32x4 ntload4(const float* p) {
    return __builtin_nontemporal_load((const f32x4*)p);
}
__device__ __forceinline__ void ntstore4(float* p, f32x4 v) {
    __builtin_nontemporal_store(v, (f32x4*)p);
}

// ---------------------------------------------------------------------------
// Pack weights into MFMA fragment order (hi/lo bf16). 65 wgs: wg blk in 0..63
// stages its 64x64 block in LDS (coalesced float4 row loads; gamma applied at
// load for Wd') and computes all 16 fragment slots; wg 64 builds the
// fixup/param table. Output bytes identical to the original scattered pack.
// blk 0..15 = R[b], 16..31 = L[c], 32..47 = Wd' = diag(gamma)Wd, 48..63 = Wu.
// Table at float offset (64*8192 ushorts): bcf[0..63]=B=gamma@Wd,
// bcf[64..127]=C=beta@Wd, bcf[128+p*8+{0..7}] = {gamma,beta,th0',th1',th2',
// ph0',ph1',ph2'} with th'/ph' pre-multiplied by 1/(2*pi).
// Frag addressing (ushorts): blk*8192 + ((kk*4+nt)*2+comp)*512 + lane*8
// element v of lane l:  M[kk*32 + (l>>4)*8 + v][nt*16 + (l&15)]
// ---------------------------------------------------------------------------
__global__ __launch_bounds__(256) void pack_weights(
    const float* __restrict__ R, const float* __restrict__ L,
    const float* __restrict__ Wd, const float* __restrict__ Wu,
    const float* __restrict__ gamma, const float* __restrict__ beta,
    const float* __restrict__ thetas, const float* __restrict__ phis,
    unsigned short* __restrict__ wsp)
{
    const int bx = blockIdx.x;
    const int tid = threadIdx.x;
    if (bx == 64) {
        float* bc = (float*)(wsp + (size_t)64 * 8192);
        const float INV2PI = 0.15915494309189535f;
        for (int i = tid; i < 1024; i += 256) {
            float* t = bc + 128 + i * 8;
            t[0] = gamma[i];                 t[1] = beta[i];
            t[2] = thetas[i] * INV2PI;       t[3] = thetas[1024 + i] * INV2PI;
            t[4] = thetas[2048 + i] * INV2PI;
            t[5] = phis[i] * INV2PI;         t[6] = phis[1024 + i] * INV2PI;
            t[7] = phis[2048 + i] * INV2PI;
        }
        __shared__ float red[8][64];
        const int r = tid & 63, part = tid >> 6;
        float sb = 0.f, sc = 0.f;
        for (int c = part * 256; c < part * 256 + 256; ++c) {
            const float w = Wd[(size_t)c * 64 + r];
            sb += gamma[c] * w;
            sc += beta[c] * w;
        }
        red[part][r] = sb; red[part + 4][r] = sc;
        __syncthreads();
        if (part == 0) {
            bc[r]      = red[0][r] + red[1][r] + red[2][r] + red[3][r];
            bc[64 + r] = red[4][r] + red[5][r] + red[6][r] + red[7][r];
        }
        return;
    }
    const int blk = bx;
    __shared__ float M[4096];                    // 64x64 f32 block, 16 KB
    // ---- stage 1: coalesced load into LDS ----
    if (blk < 16) {
        const float* src = R + (size_t)blk * 4096;
        #pragma unroll
        for (int t = tid * 4; t < 4096; t += 1024)
            *(float4*)&M[t] = *(const float4*)&src[t];
    } else if (blk < 32) {
        const float* src = L + (size_t)(blk - 16) * 4096;
        #pragma unroll
        for (int t = tid * 4; t < 4096; t += 1024)
            *(float4*)&M[t] = *(const float4*)&src[t];
    } else if (blk < 48) {
        const float* src = Wd + (size_t)(blk - 32) * 4096;
        const float* gsrc = gamma + (blk - 32) * 64;
        #pragma unroll
        for (int t = tid * 4; t < 4096; t += 1024) {
            const float gm = gsrc[t >> 6];
            float4 wv = *(const float4*)&src[t];
            wv.x *= gm; wv.y *= gm; wv.z *= gm; wv.w *= gm;
            *(float4*)&M[t] = wv;
        }
    } else {
        const float* src = Wu + (blk - 48) * 64;
        #pragma unroll
        for (int t = tid * 4; t < 4096; t += 1024) {
            const int k = t >> 6, j = t & 63;
            *(float4*)&M[t] = *(const float4*)&src[(size_t)k * 1024 + j];
        }
    }
    __syncthreads();
    // ---- stage 2: fragment packing from LDS (identical bytes to old pack) ----
    unsigned short* dst = wsp + (size_t)blk * 8192;
    for (int it = 0; it < 4; ++it) {
        const int slot = tid + it * 256;         // 0..1023
        const int fragidx = slot >> 6;           // 0..15
        const int l = slot & 63;
        const int kk = fragidx >> 3;
        const int nt = (fragidx >> 1) & 3;
        const int comp = fragidx & 1;
        const int g = l >> 4, r16 = l & 15;
        const int j = nt * 16 + r16;
        bf16x8 s;
        #pragma unroll
        for (int v = 0; v < 8; ++v) {
            const int k = kk * 32 + g * 8 + v;
            const float w = M[k * 64 + j];
            unsigned short hi = f2bf(w);
            unsigned short bits = (comp == 0) ? hi : f2bf(w - bf2f(hi));
            s[v] = (short)bits;
        }
        *(bf16x8*)(dst + fragidx * 512 + l * 8) = s;
    }
}

// ---------------------------------------------------------------------------
// Fused main kernel — R13 VERBATIM. 512 threads (8 waves), 16 tokens/wg.
// Wave w: grp = w>>2 (splits block/K loops), ntw = w&3 (16-col subtile).
// ---------------------------------------------------------------------------
__global__ __launch_bounds__(512, 4) void qrun_main(
    const float* __restrict__ x, const float* __restrict__ bias,
    const float* __restrict__ Wp, const float* __restrict__ bpv,
    const unsigned short* __restrict__ wpk, float* __restrict__ out)
{
    extern __shared__ char smem[];
    unsigned short* hiP = (unsigned short*)smem;          // [16][PITCH]
    unsigned short* loP = hiP + 16 * PITCH;               // [16][PITCH]
    float* dbuf = (float*)(loP + 16 * PITCH);             // [2][16][DPITCH]
    float* lnpart = dbuf + 2 * DHALF;                     // [8][16][2]
    float* statsR = lnpart + 256;                         // [16][2]

    const int tid = threadIdx.x;
    const int wave = tid >> 6, lane = tid & 63;
    const int g = lane >> 4, r16 = lane & 15;
    const int grp = wave >> 2, ntw = wave & 3;
    const size_t n0 = (size_t)blockIdx.x * 16;
    const int rowA = r16 * PITCH;

    // ---- phase 0: load x tile (non-temporal), split to hi/lo bf16 planes ----
    {
        const float* xb = x + n0 * 1024;
        #pragma unroll
        for (int it = 0; it < 4; ++it) {
            const int base = (it * 512 + tid) * 8;
            const int row = base >> 10, col = base & 1023;
            const f32x4 f0 = ntload4(xb + base);
            const f32x4 f1 = ntload4(xb + base + 4);
            unsigned H0, L0, H1, L1, H2, L2, H3, L3;
            split2(f0[0], f0[1], H0, L0);
            split2(f0[2], f0[3], H1, L1);
            split2(f1[0], f1[1], H2, L2);
            split2(f1[2], f1[3], H3, L3);
            *(uint4*)(hiP + row * PITCH + col) = make_uint4(H0, H1, H2, H3);
            *(uint4*)(loP + row * PITCH + col) = make_uint4(L0, L1, L2, L3);
        }
    }
    __syncthreads();

    // ---- phase 1: monarch stage 1 (x @ Rhi[b]); x-split exact, weight hi-only ----
    f32x4 acc1[8];
    #pragma unroll
    for (int bi = 0; bi < 8; ++bi) {
        const int b = grp * 8 + bi;
        const unsigned short* wb = wpk + (size_t)b * 8192;
        bf16x8 Bh0 = *(const bf16x8*)(wb + ((0*4+ntw)*2+0)*512 + lane*8);
        bf16x8 Bh1 = *(const bf16x8*)(wb + ((1*4+ntw)*2+0)*512 + lane*8);
        const int ca = b * 64 + g * 8;
        bf16x8 Ah0 = *(const bf16x8*)(hiP + rowA + ca);
        bf16x8 Al0 = *(const bf16x8*)(loP + rowA + ca);
        bf16x8 Ah1 = *(const bf16x8*)(hiP + rowA + ca + 32);
        bf16x8 Al1 = *(const bf16x8*)(loP + rowA + ca + 32);
        f32x4 a = {0.f, 0.f, 0.f, 0.f};
        a = MFMA(Ah0, Bh0, a); a = MFMA(Al0, Bh0, a);
        a = MFMA(Ah1, Bh1, a); a = MFMA(Al1, Bh1, a);
        acc1[bi] = a;
    }
    __syncthreads();   // all stage-1 reads complete before permuted overwrite

    // permuted write: D col (b*64+ntw*16+r16) -> dest col; the 8 bi land on 8
    // consecutive columns => uint4 write. g-field XOR-swizzled by (c'&3).
    {
        const int Cw = (ntw * 4 + (r16 >> 2)) * 64 + ((r16 >> 1) & 1) * 32
                     + (((grp + 2 * (r16 & 1)) ^ (r16 >> 2)) << 3);
        #pragma unroll
        for (int v = 0; v < 4; ++v) {
            const int rowv = (g * 4 + v) * PITCH;
            unsigned h0, l0, h1, l1, h2, l2, h3, l3;
            split2(acc1[0][v], acc1[1][v], h0, l0);
            split2(acc1[2][v], acc1[3][v], h1, l1);
            split2(acc1[4][v], acc1[5][v], h2, l2);
            split2(acc1[6][v], acc1[7][v], h3, l3);
            *(uint4*)(hiP + rowv + Cw) = make_uint4(h0, h1, h2, h3);
            *(uint4*)(loP + rowv + Cw) = make_uint4(l0, l1, l2, l3);
        }
    }
    __syncthreads();

    // ---- phase 2: monarch stage 2 swapped: h2^T = Lhi^T @ mid^T (mid split) ----
    f32x4 acc2[8];
    #pragma unroll
    for (int ci = 0; ci < 8; ++ci) {
        const int c = grp * 8 + ci;
        const unsigned short* wb = wpk + (size_t)(16 + c) * 8192;
        bf16x8 Wh0 = *(const bf16x8*)(wb + ((0*4+ntw)*2+0)*512 + lane*8);
        bf16x8 Wh1 = *(const bf16x8*)(wb + ((1*4+ntw)*2+0)*512 + lane*8);
        const int gx = ((g ^ (c & 3)) << 3);               // XOR swizzle (read)
        const int c0 = rowA + c * 64 + gx;                 // kk=0
        bf16x8 Hh0 = *(const bf16x8*)(hiP + c0);
        bf16x8 Hl0 = *(const bf16x8*)(loP + c0);
        bf16x8 Hh1 = *(const bf16x8*)(hiP + c0 + 32);
        bf16x8 Hl1 = *(const bf16x8*)(loP + c0 + 32);
        f32x4 a = {0.f, 0.f, 0.f, 0.f};
        a = MFMA(Wh0, Hh0, a); a = MFMA(Wh0, Hl0, a);
        a = MFMA(Wh1, Hh1, a); a = MFMA(Wh1, Hl1, a);
        acc2[ci] = a;
    }
    __syncthreads();   // all permuted-tile reads complete before overwrite

    // epilogue: +bias, write RAW h (hi/lo), LN partial sums
    {
        float s = 0.f, s2 = 0.f;
        #pragma unroll
        for (int ci = 0; ci < 8; ++ci) {
            const int c = grp * 8 + ci;
            const int ncol = c * 64 + ntw * 16 + g * 4;
            const float4 bv = *(const float4*)(bias + ncol);
            const float f0 = acc2[ci][0] + bv.x;
            const float f1 = acc2[ci][1] + bv.y;
            const float f2 = acc2[ci][2] + bv.z;
            const float f3 = acc2[ci][3] + bv.w;
            s += f0 + f1 + f2 + f3;
            s2 += f0 * f0 + f1 * f1 + f2 * f2 + f3 * f3;
            unsigned hA, lA, hB, lB;
            split2(f0, f1, hA, lA);
            split2(f2, f3, hB, lB);
            *(uint2*)(hiP + rowA + ncol) = make_uint2(hA, hB);
            *(uint2*)(loP + rowA + ncol) = make_uint2(lA, lB);
        }
        s  += __shfl_xor(s, 16);  s  += __shfl_xor(s, 32);
        s2 += __shfl_xor(s2, 16); s2 += __shfl_xor(s2, 32);
        if (g == 0) {
            lnpart[(wave * 16 + r16) * 2]     = s;
            lnpart[(wave * 16 + r16) * 2 + 1] = s2;
        }
    }
    __syncthreads();

    // ---- phase 4: down-proj on RAW h, swapped: d^T = Wd'^T @ h^T (hi-only);
    //      first 16 lanes also finish the LN stats reduce.
    if (tid < 16) {
        float s = 0.f, s2 = 0.f;
        #pragma unroll
        for (int w = 0; w < 8; ++w) {
            s  += lnpart[(w * 16 + tid) * 2];
            s2 += lnpart[(w * 16 + tid) * 2 + 1];
        }
        const float mu = s * (1.f / 1024.f);
        statsR[tid * 2]     = mu;
        statsR[tid * 2 + 1] = rsqrtf(s2 * (1.f / 1024.f) - mu * mu + 1e-5f);
    }
    {
        f32x4 accd = {0.f, 0.f, 0.f, 0.f};
        #pragma unroll
        for (int ki = 0; ki < 16; ++ki) {
            const int kq = grp * 16 + ki;
            const int kb = kq >> 1, kin = kq & 1;
            const unsigned short* wb = wpk + (size_t)(32 + kb) * 8192;
            bf16x8 Wh = *(const bf16x8*)(wb + ((kin*4+ntw)*2+0)*512 + lane*8);
            bf16x8 Hh = *(const bf16x8*)(hiP + rowA + kq * 32 + g * 8);
            accd = MFMA(Wh, Hh, accd);
        }
        // D[rank-local g*4+v][token r16]; rank r = ntw*16 + g*4 + v
        *(f32x4*)(dbuf + grp * DHALF + r16 * DPITCH + ntw * 16 + g * 4) = accd;
    }
    __syncthreads();

    // ---- phase 5: LN-fixup + up-proj + residual + sin/cos + final linear ----
    const float* bcf = (const float*)(wpk + (size_t)64 * 8192);
    const float muT = statsR[r16 * 2], rsT = statsR[r16 * 2 + 1];
    float muR[4], rsR[4];
    #pragma unroll
    for (int v = 0; v < 4; ++v) {
        muR[v] = statsR[(g * 4 + v) * 2];
        rsR[v] = statsR[(g * 4 + v) * 2 + 1];
    }
    bf16x8 dA[2];
    #pragma unroll
    for (int kk = 0; kk < 2; ++kk) {
        const int rb = kk * 32 + g * 8;
        const float4 B0 = *(const float4*)(bcf + rb);
        const float4 B1 = *(const float4*)(bcf + rb + 4);
        const float4 C0 = *(const float4*)(bcf + 64 + rb);
        const float4 C1 = *(const float4*)(bcf + 64 + rb + 4);
        const float Ba[8] = {B0.x,B0.y,B0.z,B0.w,B1.x,B1.y,B1.z,B1.w};
        const float Ca[8] = {C0.x,C0.y,C0.z,C0.w,C1.x,C1.y,C1.z,C1.w};
        const int di = r16 * DPITCH + rb;
        const f32x4 q0 = *(const f32x4*)(dbuf + di);
        const f32x4 q1 = *(const f32x4*)(dbuf + di + 4);
        const f32x4 p0 = *(const f32x4*)(dbuf + DHALF + di);
        const f32x4 p1 = *(const f32x4*)(dbuf + DHALF + di + 4);
        float dv[8];
        #pragma unroll
        for (int v = 0; v < 4; ++v) {
            dv[v]     = rsT * (q0[v] + p0[v]) - muT * rsT * Ba[v]     + Ca[v];
            dv[v + 4] = rsT * (q1[v] + p1[v]) - muT * rsT * Ba[v + 4] + Ca[v + 4];
        }
        const uint4 uu = make_uint4(cvt_pk_bf16(dv[0], dv[1]),
                                    cvt_pk_bf16(dv[2], dv[3]),
                                    cvt_pk_bf16(dv[4], dv[5]),
                                    cvt_pk_bf16(dv[6], dv[7]));
        dA[kk] = __builtin_bit_cast(bf16x8, uu);
    }
    float wp[24];
    #pragma unroll
    for (int k2 = 0; k2 < 24; ++k2) wp[k2] = Wp[k2];
    const float bp0 = bpv[0], bp1 = bpv[1], bp2 = bpv[2], bp3 = bpv[3];

    #pragma unroll 1
    for (int j = 0; j < 8; ++j) {
        const int ntg = wave * 8 + j;
        const int nb = ntg >> 2, ntin = ntg & 3;
        const unsigned short* wb = wpk + (size_t)(48 + nb) * 8192;
        bf16x8 Bh0 = *(const bf16x8*)(wb + ((0*4+ntin)*2+0)*512 + lane*8);
        bf16x8 Bh1 = *(const bf16x8*)(wb + ((1*4+ntin)*2+0)*512 + lane*8);
        f32x4 au = {0.f, 0.f, 0.f, 0.f};
        au = MFMA(dA[0], Bh0, au);
        au = MFMA(dA[1], Bh1, au);
        const int p = ntg * 16 + r16;
        const float4 t0 = *(const float4*)(bcf + 128 + p * 8);
        const float4 t1 = *(const float4*)(bcf + 128 + p * 8 + 4);
        const float gp = t0.x, bpp = t0.y;
        const float th0 = t0.z, th1 = t0.w, th2 = t1.x;
        const float ph0 = t1.y, ph1 = t1.z, ph2 = t1.w;
        #pragma unroll
        for (int v = 0; v < 4; ++v) {
            const int row = g * 4 + v;
            const float hraw = bf2f(hiP[row * PITCH + p]) + bf2f(loP[row * PITCH + p]);
            const float hn = (hraw - muR[v]) * rsR[v] * gp + bpp;
            const float e = au[v] + hn;
            float o0 = bp0, o1 = bp1, o2 = bp2, o3 = bp3;
            float arg, sn, cs;
            asm("v_fract_f32 %0, %1" : "=v"(arg) : "v"(fmaf(e, th0, ph0)));
            asm("v_sin_f32 %0, %1" : "=v"(sn) : "v"(arg));
            asm("v_cos_f32 %0, %1" : "=v"(cs) : "v"(arg));
            o0 = fmaf(sn, wp[0],  fmaf(cs, wp[1],  o0));
            o1 = fmaf(sn, wp[6],  fmaf(cs, wp[7],  o1));
            o2 = fmaf(sn, wp[12], fmaf(cs, wp[13], o2));
            o3 = fmaf(sn, wp[18], fmaf(cs, wp[19], o3));
            asm("v_fract_f32 %0, %1" : "=v"(arg) : "v"(fmaf(e, th1, ph1)));
            asm("v_sin_f32 %0, %1" : "=v"(sn) : "v"(arg));
            asm("v_cos_f32 %0, %1" : "=v"(cs) : "v"(arg));
            o0 = fmaf(sn, wp[2],  fmaf(cs, wp[3],  o0));
            o1 = fmaf(sn, wp[8],  fmaf(cs, wp[9],  o1));
            o2 = fmaf(sn, wp[14], fmaf(cs, wp[15], o2));
            o3 = fmaf(sn, wp[20], fmaf(cs, wp[21], o3));
            asm("v_fract_f32 %0, %1" : "=v"(arg) : "v"(fmaf(e, th2, ph2)));
            asm("v_sin_f32 %0, %1" : "=v"(sn) : "v"(arg));
            asm("v_cos_f32 %0, %1" : "=v"(cs) : "v"(arg));
            o0 = fmaf(sn, wp[4],  fmaf(cs, wp[5],  o0));
            o1 = fmaf(sn, wp[10], fmaf(cs, wp[11], o1));
            o2 = fmaf(sn, wp[16], fmaf(cs, wp[17], o2));
            o3 = fmaf(sn, wp[22], fmaf(cs, wp[23], o3));
            f32x4 ov = {o0, o1, o2, o3};
            ntstore4(out + ((n0 + row) * 1024 + p) * 4, ov);
        }
    }
}

extern "C" void kernel_launch(void* const* d_in, const int* in_sizes, int n_in,
                              void* d_out, int out_size, void* d_ws, size_t ws_size,
                              hipStream_t stream) {
    const float* x      = (const float*)d_in[0];
    const float* R      = (const float*)d_in[1];
    const float* L      = (const float*)d_in[2];
    const float* bias   = (const float*)d_in[3];
    const float* gamma  = (const float*)d_in[4];
    const float* beta   = (const float*)d_in[5];
    const float* Wd     = (const float*)d_in[6];
    const float* Wu     = (const float*)d_in[7];
    const float* thetas = (const float*)d_in[8];
    const float* phis   = (const float*)d_in[9];
    const float* Wp     = (const float*)d_in[10];
    const float* bp     = (const float*)d_in[11];
    float* out = (float*)d_out;
    unsigned short* wsp = (unsigned short*)d_ws;
    const int N = in_sizes[0] / 1024;   // 8192 tokens

    (void)hipFuncSetAttribute((const void*)qrun_main,
                              hipFuncAttributeMaxDynamicSharedMemorySize, SMEM_BYTES);
    pack_weights<<<dim3(65), dim3(256), 0, stream>>>(R, L, Wd, Wu, gamma, beta,
                                                     thetas, phis, wsp);
    qrun_main<<<dim3(N / 16), dim3(512), SMEM_BYTES, stream>>>(
        x, bias, Wp, bp, wsp, out);
}

// Round 19
// 50.747 us; speedup vs baseline: 1.5377x; 1.0360x over previous
//
#include <hip/hip_runtime.h>

// Q_RUNLayer_Hybrid: monarch(blockdiag R -> stride perm -> blockdiag L) + bias
// -> LayerNorm -> h + (h@Wd)@Wu -> sin/cos reupload (3) -> [PROJ,6]@Wp.T+bp
// R19: SINGLE fp16 plane end-to-end (no hi/lo machinery at all — the bf16
// hi+lo payload failed 3x for unfindable reasons; fp16 2^-11 needs no
// residual). fp16 MFMAs (16x16x32_f16, same frag layout). 42.9 KB LDS ->
// 3 wg/CU via launch_bounds(512,6) + SGPR-hoisted wp/bp. All structure
// (barrier chain, f32 dbuf, lnpart reduce, asm trig, nt loads/stores,
// coalesced pack) copied verbatim from green R13/R17.

typedef __attribute__((ext_vector_type(8))) _Float16 f16x8;
typedef __attribute__((ext_vector_type(4))) _Float16 f16x4;
typedef __attribute__((ext_vector_type(4))) float f32x4;

#define PITCH 1032            // ushorts per fp16-plane row (1024 + 8 pad)
#define DPITCH 68             // floats per dbuf row
#define DHALF (16 * DPITCH)   // 1088
#define SMEM_BYTES 42880      // 33024 + 8704 + 1024 + 128

__device__ __forceinline__ f32x4 MFMA16(f16x8 a, f16x8 b, f32x4 c) {
    return __builtin_amdgcn_mfma_f32_16x16x32_f16(a, b, c, 0, 0, 0);
}
__device__ __forceinline__ float uniformf(float f) {
    return __uint_as_float(__builtin_amdgcn_readfirstlane(__float_as_uint(f)));
}
__device__ __forceinline__ f32x4 ntload4(const float* p) {
    return __builtin_nontemporal_load((const f32x4*)p);
}
__device__ __forceinline__ void ntstore4(float* p, f32x4 v) {
    __builtin_nontemporal_store(v, (f32x4*)p);
}

// ---------------------------------------------------------------------------
// Pack weights into fp16 MFMA fragment order. 65 wgs (coalesced, R17 shape):
// wg blk 0..63 stages its 64x64 f32 block in LDS (gamma applied for Wd'),
// then writes fragment slots; wg 64 builds the fixup/param table.
// blk 0..15 = R[b], 16..31 = L[c], 32..47 = Wd' = diag(gamma)Wd, 48..63 = Wu.
// Frag addressing (ushorts): blk*8192 + ((kk*4+nt)*2+0)*512 + lane*8
// element v of lane l:  M[kk*32 + (l>>4)*8 + v][nt*16 + (l&15)]   (fp16 bits)
// comp=1 slots are zero-filled (unused).
// Table at float offset (64*8192 ushorts): bcf[0..63]=B=gamma@Wd,
// bcf[64..127]=C=beta@Wd, bcf[128+p*8+{0..7}] = {gamma,beta,th0',th1',th2',
// ph0',ph1',ph2'} with th'/ph' pre-multiplied by 1/(2*pi).
// ---------------------------------------------------------------------------
__global__ __launch_bounds__(256) void pack_weights(
    const float* __restrict__ R, const float* __restrict__ L,
    const float* __restrict__ Wd, const float* __restrict__ Wu,
    const float* __restrict__ gamma, const float* __restrict__ beta,
    const float* __restrict__ thetas, const float* __restrict__ phis,
    unsigned short* __restrict__ wsp)
{
    const int bx = blockIdx.x;
    const int tid = threadIdx.x;
    if (bx == 64) {
        float* bc = (float*)(wsp + (size_t)64 * 8192);
        const float INV2PI = 0.15915494309189535f;
        for (int i = tid; i < 1024; i += 256) {
            float* t = bc + 128 + i * 8;
            t[0] = gamma[i];                 t[1] = beta[i];
            t[2] = thetas[i] * INV2PI;       t[3] = thetas[1024 + i] * INV2PI;
            t[4] = thetas[2048 + i] * INV2PI;
            t[5] = phis[i] * INV2PI;         t[6] = phis[1024 + i] * INV2PI;
            t[7] = phis[2048 + i] * INV2PI;
        }
        __shared__ float red[8][64];
        const int r = tid & 63, part = tid >> 6;
        float sb = 0.f, sc = 0.f;
        for (int c = part * 256; c < part * 256 + 256; ++c) {
            const float w = Wd[(size_t)c * 64 + r];
            sb += gamma[c] * w;
            sc += beta[c] * w;
        }
        red[part][r] = sb; red[part + 4][r] = sc;
        __syncthreads();
        if (part == 0) {
            bc[r]      = red[0][r] + red[1][r] + red[2][r] + red[3][r];
            bc[64 + r] = red[4][r] + red[5][r] + red[6][r] + red[7][r];
        }
        return;
    }
    const int blk = bx;
    __shared__ float M[4096];                    // 64x64 f32 block, 16 KB
    if (blk < 16) {
        const float* src = R + (size_t)blk * 4096;
        #pragma unroll
        for (int t = tid * 4; t < 4096; t += 1024)
            *(float4*)&M[t] = *(const float4*)&src[t];
    } else if (blk < 32) {
        const float* src = L + (size_t)(blk - 16) * 4096;
        #pragma unroll
        for (int t = tid * 4; t < 4096; t += 1024)
            *(float4*)&M[t] = *(const float4*)&src[t];
    } else if (blk < 48) {
        const float* src = Wd + (size_t)(blk - 32) * 4096;
        const float* gsrc = gamma + (blk - 32) * 64;
        #pragma unroll
        for (int t = tid * 4; t < 4096; t += 1024) {
            const float gm = gsrc[t >> 6];
            float4 wv = *(const float4*)&src[t];
            wv.x *= gm; wv.y *= gm; wv.z *= gm; wv.w *= gm;
            *(float4*)&M[t] = wv;
        }
    } else {
        const float* src = Wu + (blk - 48) * 64;
        #pragma unroll
        for (int t = tid * 4; t < 4096; t += 1024) {
            const int k = t >> 6, j = t & 63;
            *(float4*)&M[t] = *(const float4*)&src[(size_t)k * 1024 + j];
        }
    }
    __syncthreads();
    unsigned short* dst = wsp + (size_t)blk * 8192;
    for (int it = 0; it < 4; ++it) {
        const int slot = tid + it * 256;         // 0..1023
        const int fragidx = slot >> 6;           // 0..15
        const int l = slot & 63;
        const int kk = fragidx >> 3;
        const int nt = (fragidx >> 1) & 3;
        const int comp = fragidx & 1;
        const int g = l >> 4, r16 = l & 15;
        const int j = nt * 16 + r16;
        f16x8 s;
        #pragma unroll
        for (int v = 0; v < 8; ++v) {
            const int k = kk * 32 + g * 8 + v;
            const float w = M[k * 64 + j];
            s[v] = (comp == 0) ? (_Float16)w : (_Float16)0.f;
        }
        *(uint4*)(dst + fragidx * 512 + l * 8) = __builtin_bit_cast(uint4, s);
    }
}

// ---------------------------------------------------------------------------
// Fused main kernel. 512 threads (8 waves), 16 tokens per workgroup, 3 wg/CU.
// Wave w: grp = w>>2 (splits block/K loops), ntw = w&3 (16-col subtile).
// ---------------------------------------------------------------------------
__global__ __launch_bounds__(512, 6) void qrun_main(
    const float* __restrict__ x, const float* __restrict__ bias,
    const float* __restrict__ Wp, const float* __restrict__ bpv,
    const unsigned short* __restrict__ wpk, float* __restrict__ out)
{
    extern __shared__ char smem[];
    unsigned short* plane = (unsigned short*)smem;        // [16][PITCH] fp16
    float* dbuf = (float*)(smem + 33024);                 // [2][16][DPITCH] f32
    float* lnpart = (float*)(smem + 41728);               // [8][16][2]
    float* statsR = (float*)(smem + 42752);               // [16][2] (mu, rs)

    const int tid = threadIdx.x;
    const int wave = tid >> 6, lane = tid & 63;
    const int g = lane >> 4, r16 = lane & 15;
    const int grp = wave >> 2, ntw = wave & 3;
    const size_t n0 = (size_t)blockIdx.x * 16;
    const int rowA = r16 * PITCH;

    // ---- phase 0: load x (nt), fp16 into plane ----
    {
        const float* xb = x + n0 * 1024;
        #pragma unroll
        for (int it = 0; it < 4; ++it) {
            const int base = (it * 512 + tid) * 8;
            const int row = base >> 10, col = base & 1023;
            const f32x4 f0 = ntload4(xb + base);
            const f32x4 f1 = ntload4(xb + base + 4);
            f16x8 hv;
            hv[0] = (_Float16)f0[0]; hv[1] = (_Float16)f0[1];
            hv[2] = (_Float16)f0[2]; hv[3] = (_Float16)f0[3];
            hv[4] = (_Float16)f1[0]; hv[5] = (_Float16)f1[1];
            hv[6] = (_Float16)f1[2]; hv[7] = (_Float16)f1[3];
            *(uint4*)(plane + row * PITCH + col) = __builtin_bit_cast(uint4, hv);
        }
    }
    __syncthreads();

    // ---- phase 1: monarch stage 1 (x @ R[b]), fp16 ----
    f32x4 acc1[8];
    #pragma unroll
    for (int bi = 0; bi < 8; ++bi) {
        const int b = grp * 8 + bi;
        const unsigned short* wb = wpk + (size_t)b * 8192;
        f16x8 Bh0 = *(const f16x8*)(wb + ((0*4+ntw)*2+0)*512 + lane*8);
        f16x8 Bh1 = *(const f16x8*)(wb + ((1*4+ntw)*2+0)*512 + lane*8);
        const int ca = b * 64 + g * 8;
        f16x8 Ah0 = *(const f16x8*)(plane + rowA + ca);
        f16x8 Ah1 = *(const f16x8*)(plane + rowA + ca + 32);
        f32x4 a = {0.f, 0.f, 0.f, 0.f};
        a = MFMA16(Ah0, Bh0, a);
        a = MFMA16(Ah1, Bh1, a);
        acc1[bi] = a;
    }
    __syncthreads();   // all stage-1 reads complete before permuted overwrite

    // permuted write: D col (b*64+ntw*16+r16) -> dest col; the 8 bi land on 8
    // consecutive columns => uint4 write. g-field XOR-swizzled by (c'&3).
    {
        const int Cw = (ntw * 4 + (r16 >> 2)) * 64 + ((r16 >> 1) & 1) * 32
                     + (((grp + 2 * (r16 & 1)) ^ (r16 >> 2)) << 3);
        #pragma unroll
        for (int v = 0; v < 4; ++v) {
            const int rowv = (g * 4 + v) * PITCH;
            f16x8 hv;
            hv[0] = (_Float16)acc1[0][v]; hv[1] = (_Float16)acc1[1][v];
            hv[2] = (_Float16)acc1[2][v]; hv[3] = (_Float16)acc1[3][v];
            hv[4] = (_Float16)acc1[4][v]; hv[5] = (_Float16)acc1[5][v];
            hv[6] = (_Float16)acc1[6][v]; hv[7] = (_Float16)acc1[7][v];
            *(uint4*)(plane + rowv + Cw) = __builtin_bit_cast(uint4, hv);
        }
    }
    __syncthreads();

    // ---- phase 2: monarch stage 2 swapped: h2^T = L^T @ mid^T, fp16 ----
    f32x4 acc2[8];
    #pragma unroll
    for (int ci = 0; ci < 8; ++ci) {
        const int c = grp * 8 + ci;
        const unsigned short* wb = wpk + (size_t)(16 + c) * 8192;
        f16x8 Wh0 = *(const f16x8*)(wb + ((0*4+ntw)*2+0)*512 + lane*8);
        f16x8 Wh1 = *(const f16x8*)(wb + ((1*4+ntw)*2+0)*512 + lane*8);
        const int gx = ((g ^ (c & 3)) << 3);               // XOR swizzle (read)
        const int c0 = rowA + c * 64 + gx;                 // kk=0
        f16x8 Hh0 = *(const f16x8*)(plane + c0);
        f16x8 Hh1 = *(const f16x8*)(plane + c0 + 32);
        f32x4 a = {0.f, 0.f, 0.f, 0.f};
        a = MFMA16(Wh0, Hh0, a);
        a = MFMA16(Wh1, Hh1, a);
        acc2[ci] = a;
    }
    __syncthreads();   // all permuted-tile reads complete before overwrite

    // epilogue: +bias, write h (fp16), LN partial sums (from f32 values)
    {
        float s = 0.f, s2 = 0.f;
        #pragma unroll
        for (int ci = 0; ci < 8; ++ci) {
            const int c = grp * 8 + ci;
            const int ncol = c * 64 + ntw * 16 + g * 4;
            const float4 bv = *(const float4*)(bias + ncol);
            const float f0 = acc2[ci][0] + bv.x;
            const float f1 = acc2[ci][1] + bv.y;
            const float f2 = acc2[ci][2] + bv.z;
            const float f3 = acc2[ci][3] + bv.w;
            s += f0 + f1 + f2 + f3;
            s2 += f0 * f0 + f1 * f1 + f2 * f2 + f3 * f3;
            f16x4 hq;
            hq[0] = (_Float16)f0; hq[1] = (_Float16)f1;
            hq[2] = (_Float16)f2; hq[3] = (_Float16)f3;
            *(uint2*)(plane + rowA + ncol) = __builtin_bit_cast(uint2, hq);
        }
        s  += __shfl_xor(s, 16);  s  += __shfl_xor(s, 32);
        s2 += __shfl_xor(s2, 16); s2 += __shfl_xor(s2, 32);
        if (g == 0) {
            lnpart[(wave * 16 + r16) * 2]     = s;
            lnpart[(wave * 16 + r16) * 2 + 1] = s2;
        }
    }
    __syncthreads();

    // ---- phase 4: down-proj d^T = Wd'^T @ h^T (fp16); 16 lanes finish stats ----
    if (tid < 16) {
        float s = 0.f, s2 = 0.f;
        #pragma unroll
        for (int w = 0; w < 8; ++w) {
            s  += lnpart[(w * 16 + tid) * 2];
            s2 += lnpart[(w * 16 + tid) * 2 + 1];
        }
        const float mu = s * (1.f / 1024.f);
        statsR[tid * 2]     = mu;
        statsR[tid * 2 + 1] = rsqrtf(s2 * (1.f / 1024.f) - mu * mu + 1e-5f);
    }
    {
        f32x4 accd = {0.f, 0.f, 0.f, 0.f};
        #pragma unroll
        for (int ki = 0; ki < 16; ++ki) {
            const int kq = grp * 16 + ki;
            const int kb = kq >> 1, kin = kq & 1;
            const unsigned short* wb = wpk + (size_t)(32 + kb) * 8192;
            f16x8 Wh = *(const f16x8*)(wb + ((kin*4+ntw)*2+0)*512 + lane*8);
            f16x8 Hh = *(const f16x8*)(plane + rowA + kq * 32 + g * 8);
            accd = MFMA16(Wh, Hh, accd);
        }
        // D[rank-local g*4+v][token r16]; rank r = ntw*16 + g*4 + v
        *(f32x4*)(dbuf + grp * DHALF + r16 * DPITCH + ntw * 16 + g * 4) = accd;
    }
    __syncthreads();

    // ---- phase 5: LN-fixup + up-proj + residual + sin/cos + final linear ----
    const float* bcf = (const float*)(wpk + (size_t)64 * 8192);
    const float muT = statsR[r16 * 2], rsT = statsR[r16 * 2 + 1];
    float muR[4], rsR[4];
    #pragma unroll
    for (int v = 0; v < 4; ++v) {
        muR[v] = statsR[(g * 4 + v) * 2];
        rsR[v] = statsR[(g * 4 + v) * 2 + 1];
    }
    f16x8 dA[2];
    #pragma unroll
    for (int kk = 0; kk < 2; ++kk) {
        const int rb = kk * 32 + g * 8;
        const float4 B0 = *(const float4*)(bcf + rb);
        const float4 B1 = *(const float4*)(bcf + rb + 4);
        const float4 C0 = *(const float4*)(bcf + 64 + rb);
        const float4 C1 = *(const float4*)(bcf + 64 + rb + 4);
        const float Ba[8] = {B0.x,B0.y,B0.z,B0.w,B1.x,B1.y,B1.z,B1.w};
        const float Ca[8] = {C0.x,C0.y,C0.z,C0.w,C1.x,C1.y,C1.z,C1.w};
        const int di = r16 * DPITCH + rb;
        const f32x4 q0 = *(const f32x4*)(dbuf + di);
        const f32x4 q1 = *(const f32x4*)(dbuf + di + 4);
        const f32x4 p0 = *(const f32x4*)(dbuf + DHALF + di);
        const f32x4 p1 = *(const f32x4*)(dbuf + DHALF + di + 4);
        f16x8 dq;
        #pragma unroll
        for (int v = 0; v < 4; ++v) {
            dq[v]     = (_Float16)(rsT * (q0[v] + p0[v]) - muT * rsT * Ba[v]     + Ca[v]);
            dq[v + 4] = (_Float16)(rsT * (q1[v] + p1[v]) - muT * rsT * Ba[v + 4] + Ca[v + 4]);
        }
        dA[kk] = dq;
    }
    float wp[24];
    #pragma unroll
    for (int k2 = 0; k2 < 24; ++k2) wp[k2] = uniformf(Wp[k2]);
    const float bp0 = uniformf(bpv[0]), bp1 = uniformf(bpv[1]);
    const float bp2 = uniformf(bpv[2]), bp3 = uniformf(bpv[3]);

    #pragma unroll 1
    for (int j = 0; j < 8; ++j) {
        const int ntg = wave * 8 + j;
        const int nb = ntg >> 2, ntin = ntg & 3;
        const unsigned short* wb = wpk + (size_t)(48 + nb) * 8192;
        f16x8 Bh0 = *(const f16x8*)(wb + ((0*4+ntin)*2+0)*512 + lane*8);
        f16x8 Bh1 = *(const f16x8*)(wb + ((1*4+ntin)*2+0)*512 + lane*8);
        f32x4 au = {0.f, 0.f, 0.f, 0.f};
        au = MFMA16(dA[0], Bh0, au);
        au = MFMA16(dA[1], Bh1, au);
        const int p = ntg * 16 + r16;
        const float4 t0 = *(const float4*)(bcf + 128 + p * 8);
        const float4 t1 = *(const float4*)(bcf + 128 + p * 8 + 4);
        const float gp = t0.x, bpp = t0.y;
        const float th0 = t0.z, th1 = t0.w, th2 = t1.x;
        const float ph0 = t1.y, ph1 = t1.z, ph2 = t1.w;
        #pragma unroll
        for (int v = 0; v < 4; ++v) {
            const int row = g * 4 + v;
            const float hraw = (float)*(const _Float16*)(plane + row * PITCH + p);
            const float hn = (hraw - muR[v]) * rsR[v] * gp + bpp;
            const float e = au[v] + hn;
            float o0 = bp0, o1 = bp1, o2 = bp2, o3 = bp3;
            float arg, sn, cs;
            asm("v_fract_f32 %0, %1" : "=v"(arg) : "v"(fmaf(e, th0, ph0)));
            asm("v_sin_f32 %0, %1" : "=v"(sn) : "v"(arg));
            asm("v_cos_f32 %0, %1" : "=v"(cs) : "v"(arg));
            o0 = fmaf(sn, wp[0],  fmaf(cs, wp[1],  o0));
            o1 = fmaf(sn, wp[6],  fmaf(cs, wp[7],  o1));
            o2 = fmaf(sn, wp[12], fmaf(cs, wp[13], o2));
            o3 = fmaf(sn, wp[18], fmaf(cs, wp[19], o3));
            asm("v_fract_f32 %0, %1" : "=v"(arg) : "v"(fmaf(e, th1, ph1)));
            asm("v_sin_f32 %0, %1" : "=v"(sn) : "v"(arg));
            asm("v_cos_f32 %0, %1" : "=v"(cs) : "v"(arg));
            o0 = fmaf(sn, wp[2],  fmaf(cs, wp[3],  o0));
            o1 = fmaf(sn, wp[8],  fmaf(cs, wp[9],  o1));
            o2 = fmaf(sn, wp[14], fmaf(cs, wp[15], o2));
            o3 = fmaf(sn, wp[20], fmaf(cs, wp[21], o3));
            asm("v_fract_f32 %0, %1" : "=v"(arg) : "v"(fmaf(e, th2, ph2)));
            asm("v_sin_f32 %0, %1" : "=v"(sn) : "v"(arg));
            asm("v_cos_f32 %0, %1" : "=v"(cs) : "v"(arg));
            o0 = fmaf(sn, wp[4],  fmaf(cs, wp[5],  o0));
            o1 = fmaf(sn, wp[10], fmaf(cs, wp[11], o1));
            o2 = fmaf(sn, wp[16], fmaf(cs, wp[17], o2));
            o3 = fmaf(sn, wp[22], fmaf(cs, wp[23], o3));
            f32x4 ov = {o0, o1, o2, o3};
            ntstore4(out + ((n0 + row) * 1024 + p) * 4, ov);
        }
    }
}

extern "C" void kernel_launch(void* const* d_in, const int* in_sizes, int n_in,
                              void* d_out, int out_size, void* d_ws, size_t ws_size,
                              hipStream_t stream) {
    const float* x      = (const float*)d_in[0];
    const float* R      = (const float*)d_in[1];
    const float* L      = (const float*)d_in[2];
    const float* bias   = (const float*)d_in[3];
    const float* gamma  = (const float*)d_in[4];
    const float* beta   = (const float*)d_in[5];
    const float* Wd     = (const float*)d_in[6];
    const float* Wu     = (const float*)d_in[7];
    const float* thetas = (const float*)d_in[8];
    const float* phis   = (const float*)d_in[9];
    const float* Wp     = (const float*)d_in[10];
    const float* bp     = (const float*)d_in[11];
    float* out = (float*)d_out;
    unsigned short* wsp = (unsigned short*)d_ws;
    const int N = in_sizes[0] / 1024;   // 8192 tokens

    (void)hipFuncSetAttribute((const void*)qrun_main,
                              hipFuncAttributeMaxDynamicSharedMemorySize, SMEM_BYTES);
    pack_weights<<<dim3(65), dim3(256), 0, stream>>>(R, L, Wd, Wu, gamma, beta,
                                                     thetas, phis, wsp);
    qrun_main<<<dim3(N / 16), dim3(512), SMEM_BYTES, stream>>>(
        x, bias, Wp, bp, wsp, out);
}